// Round 1
// baseline (441.377 us; speedup 1.0000x reference)
//
#include <hip/hip_runtime.h>

#define DI __device__ __forceinline__

typedef __bf16 bf16_t;
typedef bf16_t bf16x8 __attribute__((ext_vector_type(8)));
typedef float f32x4 __attribute__((ext_vector_type(4)));

static constexpr int NNODE = 100, WIN = 128, GH = 256, DH = 64, OUTC = 128, NB = 256;
static constexpr int NTOT = NB * NNODE;   // 25600
static constexpr int NE = 409600;
static constexpr int FFK = 6 * WIN;       // 768

DI ushort f2bf(float f) {
  union { float f; unsigned u; } v; v.f = f;
  unsigned r = v.u + 0x7fffu + ((v.u >> 16) & 1u);
  return (ushort)(r >> 16);
}
DI float bf2f(ushort s) {
  union { unsigned u; float f; } v; v.u = ((unsigned)s) << 16; return v.f;
}

DI void gload16(const void* g, void* l) {
  __builtin_amdgcn_global_load_lds((const __attribute__((address_space(1))) void*)g,
                                   (__attribute__((address_space(3))) void*)l, 16, 0, 0);
}

// ---------- weight conversion f32 -> bf16 (Wff, Wd, Wfc, Wg) ----------
__global__ void cvt_k(const float* __restrict__ s0, const float* __restrict__ s1,
                      const float* __restrict__ s2, const float* __restrict__ s3,
                      ushort* __restrict__ d0, ushort* __restrict__ d1,
                      ushort* __restrict__ d2, ushort* __restrict__ d3) {
  int j = blockIdx.x * 256 + threadIdx.x;   // vec4 index
  const float* s; ushort* d;
  if (j < 19660800 / 4) { s = s0; d = d0; }
  else if ((j -= 19660800 / 4) < 3276800 / 4) { s = s1; d = d1; }
  else if ((j -= 3276800 / 4) < 819200 / 4) { s = s2; d = d2; }
  else { j -= 819200 / 4; s = s3; d = d3; }
  float4 v = reinterpret_cast<const float4*>(s)[j];
  ushort4 o;
  o.x = f2bf(v.x); o.y = f2bf(v.y); o.z = f2bf(v.z); o.w = f2bf(v.w);
  reinterpret_cast<ushort4*>(d)[j] = o;
}

// ---------- multiscale conv (per node, 1->2ch, k=3/5/7, same pad) + relu -> c bf16 ----------
// c layout: [node][b][768], f = cidx*128 + w, cidx = {c3ch0,c3ch1,c5ch0,c5ch1,c7ch0,c7ch1}
__global__ __launch_bounds__(128) void conv_k(
    const float* __restrict__ x,
    const float* __restrict__ w3, const float* __restrict__ b3,
    const float* __restrict__ w5, const float* __restrict__ b5,
    const float* __restrict__ w7, const float* __restrict__ b7,
    ushort* __restrict__ c) {
  int r = blockIdx.x;                 // r = b*100 + node
  int b = r / 100, node = r - b * 100;
  __shared__ float xs[136];
  int w = threadIdx.x;
  xs[4 + w] = x[r * WIN + w];
  if (w < 4) { xs[w] = 0.f; xs[132 + w] = 0.f; }
  __syncthreads();
  float v[7];
#pragma unroll
  for (int j = 0; j < 7; ++j) v[j] = xs[1 + w + j];   // x[w-3+j]
  const float* W3 = w3 + node * 6;  const float* B3 = b3 + node * 2;
  const float* W5 = w5 + node * 10; const float* B5 = b5 + node * 2;
  const float* W7 = w7 + node * 14; const float* B7 = b7 + node * 2;
  ushort* out = c + (size_t)(node * NB + b) * FFK + w;
#pragma unroll
  for (int ch = 0; ch < 2; ++ch) {
    float a3 = B3[ch], a5 = B5[ch], a7 = B7[ch];
#pragma unroll
    for (int j = 0; j < 3; ++j) a3 += W3[ch * 3 + j] * v[2 + j];
#pragma unroll
    for (int j = 0; j < 5; ++j) a5 += W5[ch * 5 + j] * v[1 + j];
#pragma unroll
    for (int j = 0; j < 7; ++j) a7 += W7[ch * 7 + j] * v[j];
    out[(0 + ch) * WIN] = f2bf(fmaxf(a3, 0.f));
    out[(2 + ch) * WIN] = f2bf(fmaxf(a5, 0.f));
    out[(4 + ch) * WIN] = f2bf(fmaxf(a7, 0.f));
  }
}

// ---------- degree histogram ----------
__global__ void hist_k(const int* __restrict__ dst, int* __restrict__ deg) {
  int i = blockIdx.x * 256 + threadIdx.x;
  if (i < NE) atomicAdd(&deg[dst[i]], 1);
}

// ---------- single-block scan: offs/cursor/norm ----------
__global__ __launch_bounds__(1024) void scan_k(const int* __restrict__ deg, int* __restrict__ offs,
                                               int* __restrict__ cursor, float* __restrict__ norm) {
  __shared__ int part[1024];
  int t = threadIdx.x;
  int base = t * 25;
  int local[25];
  int s = 0;
#pragma unroll
  for (int j = 0; j < 25; ++j) { local[j] = s; s += deg[base + j]; }
  part[t] = s;
  __syncthreads();
  for (int d = 1; d < 1024; d <<= 1) {
    int vv = (t >= d) ? part[t - d] : 0;
    __syncthreads();
    part[t] += vv;
    __syncthreads();
  }
  int excl = (t > 0) ? part[t - 1] : 0;
#pragma unroll
  for (int j = 0; j < 25; ++j) {
    int o = excl + local[j];
    offs[base + j] = o;
    cursor[base + j] = o;
    norm[base + j] = rsqrtf((float)(deg[base + j] + 1));   // +1 self loop
  }
  if (t == 1023) offs[NTOT] = part[1023];
}

// ---------- CSR fill ----------
__global__ void fill_k(const int* __restrict__ src, const int* __restrict__ dst,
                       int* __restrict__ cursor, int* __restrict__ csr) {
  int i = blockIdx.x * 256 + threadIdx.x;
  if (i < NE) {
    int d = dst[i];
    int pos = atomicAdd(&cursor[d], 1);
    csr[pos] = src[i];
  }
}

// ---------- GCN aggregation: one wave per dst node ----------
__global__ __launch_bounds__(256) void agg_k(const ushort* __restrict__ xw, const int* __restrict__ offs,
                                             const int* __restrict__ csr, const float* __restrict__ norm,
                                             const float* __restrict__ bg, ushort* __restrict__ hg) {
  int v = blockIdx.x * 4 + (threadIdx.x >> 6);
  int lane = threadIdx.x & 63;
  int col = lane * 4;
  float nv = norm[v];
  ushort4 q0 = *reinterpret_cast<const ushort4*>(xw + (size_t)v * GH + col);
  float c0 = nv * nv;  // self loop coef
  float a0 = c0 * bf2f(q0.x), a1 = c0 * bf2f(q0.y), a2 = c0 * bf2f(q0.z), a3 = c0 * bf2f(q0.w);
  int e0 = offs[v], e1 = offs[v + 1];
  for (int j = e0; j < e1; ++j) {
    int s = csr[j];
    float cf = nv * norm[s];
    ushort4 q = *reinterpret_cast<const ushort4*>(xw + (size_t)s * GH + col);
    a0 += cf * bf2f(q.x); a1 += cf * bf2f(q.y); a2 += cf * bf2f(q.z); a3 += cf * bf2f(q.w);
  }
  float4 bb = reinterpret_cast<const float4*>(bg)[lane];
  ushort4 o;
  o.x = f2bf(fmaxf(a0 + bb.x, 0.f));
  o.y = f2bf(fmaxf(a1 + bb.y, 0.f));
  o.z = f2bf(fmaxf(a2 + bb.z, 0.f));
  o.w = f2bf(fmaxf(a3 + bb.w, 0.f));
  *reinterpret_cast<ushort4*>(hg + (size_t)v * GH + col) = o;
}

// ---------- BT GEMM, 128xBN tile, BK=64, global_load_lds staging ----------
// MODE 0: h[b*100+node] = relu(c[node] @ Wff[node]^T + bff[node])   M=256/node, N=256, K=768
// MODE 1: xw = h @ Wg^T                                             M=25600, N=256, K=256
// MODE 2: du[b][node*64+] = relu(cat(h1g,h2g) @ Wd[node]^T + bd)    M=256/node, N=64, K=512
// MODE 3: out += du @ Wfc^T (+bfc on ks==0), K-split atomics        M=256, N=128, K=6400
template <int MODE>
__global__ __launch_bounds__(256) void gemm_k(const ushort* __restrict__ A, const ushort* __restrict__ A2,
                                              const ushort* __restrict__ Bm, ushort* __restrict__ obf,
                                              float* __restrict__ of, const float* __restrict__ bias) {
  constexpr int BN = (MODE == 2) ? 64 : 128;
  constexpr int KT = (MODE == 0) ? 12 : (MODE == 1) ? 4 : (MODE == 2) ? 8 : 10;
  constexpr int LDA = (MODE == 0) ? 768 : (MODE == 1) ? 256 : (MODE == 2) ? 256 : 6400;
  constexpr int LDB = (MODE == 0) ? 768 : (MODE == 1) ? 256 : (MODE == 2) ? 512 : 6400;
  constexpr int MF = (MODE == 2) ? 2 : 4;
  constexpr int NF = 4;

  __shared__ ushort As[128 * 64];
  __shared__ ushort Bs[BN * 64];

  const int tid = threadIdx.x, wv = tid >> 6, lane = tid & 63;

  int mt = 0, nt = 0, node = 0, kbase = 0;
  if constexpr (MODE == 0) { mt = blockIdx.x >> 1; nt = blockIdx.x & 1; node = blockIdx.y; }
  else if constexpr (MODE == 1) { mt = blockIdx.x >> 1; nt = blockIdx.x & 1; }
  else if constexpr (MODE == 2) { mt = blockIdx.x; node = blockIdx.y; }
  else { mt = blockIdx.x; kbase = blockIdx.y * 640; }

  const ushort* Ab = nullptr; const ushort* Bb = nullptr;
  if constexpr (MODE == 0) { Ab = A + (size_t)node * (NB * FFK) + (size_t)mt * 128 * FFK;
                             Bb = Bm + (size_t)node * (GH * FFK) + (size_t)nt * 128 * FFK; }
  else if constexpr (MODE == 1) { Ab = A + (size_t)mt * 128 * GH; Bb = Bm + (size_t)nt * 128 * GH; }
  else if constexpr (MODE == 2) { Bb = Bm + (size_t)node * (DH * 512); }
  else { Ab = A + (size_t)mt * 128 * 6400 + kbase; Bb = Bm + kbase; }

  const int wr = (MODE == 2) ? wv : (wv >> 1);
  const int wc = (MODE == 2) ? 0 : (wv & 1);

  f32x4 acc[MF][NF] = {};

  for (int kt = 0; kt < KT; ++kt) {
    const int k0 = kt * 64;
    __syncthreads();
    // stage A tile: 128 rows x 64 cols bf16
#pragma unroll
    for (int it = 0; it < 4; ++it) {
      int rb = it * 32 + wv * 8;
      int row = rb + (lane >> 3);
      const ushort* gp;
      if constexpr (MODE == 2) {
        int b_ = mt * 128 + row;
        const ushort* src = (k0 < 256) ? A : A2;
        gp = src + (size_t)(b_ * NNODE + node) * GH + (k0 & 255) + (lane & 7) * 8;
      } else {
        gp = Ab + (size_t)row * LDA + k0 + (lane & 7) * 8;
      }
      gload16(gp, &As[rb * 64]);
    }
    // stage B tile: BN rows x 64 cols
#pragma unroll
    for (int it = 0; it < BN / 32; ++it) {
      int rb = it * 32 + wv * 8;
      int row = rb + (lane >> 3);
      gload16(Bb + (size_t)row * LDB + k0 + (lane & 7) * 8, &Bs[rb * 64]);
    }
    __syncthreads();
#pragma unroll
    for (int kk = 0; kk < 2; ++kk) {
      bf16x8 af[MF], bfr[NF];
#pragma unroll
      for (int m = 0; m < MF; ++m) {
        int rr = wr * (MF * 16) + m * 16 + (lane & 15);
        af[m] = *reinterpret_cast<const bf16x8*>(&As[rr * 64 + kk * 32 + (lane >> 4) * 8]);
      }
#pragma unroll
      for (int n = 0; n < NF; ++n) {
        int rr = wc * 64 + n * 16 + (lane & 15);
        bfr[n] = *reinterpret_cast<const bf16x8*>(&Bs[rr * 64 + kk * 32 + (lane >> 4) * 8]);
      }
#pragma unroll
      for (int m = 0; m < MF; ++m)
#pragma unroll
        for (int n = 0; n < NF; ++n)
          acc[m][n] = __builtin_amdgcn_mfma_f32_16x16x32_bf16(af[m], bfr[n], acc[m][n], 0, 0, 0);
    }
  }

  const int lrow = (lane >> 4) * 4, lcol = lane & 15;
#pragma unroll
  for (int m = 0; m < MF; ++m) {
#pragma unroll
    for (int n = 0; n < NF; ++n) {
      int cc = wc * 64 + n * 16 + lcol;
#pragma unroll
      for (int rg = 0; rg < 4; ++rg) {
        int rr = wr * (MF * 16) + m * 16 + lrow + rg;
        float val = acc[m][n][rg];
        if constexpr (MODE == 0) {
          int b_ = mt * 128 + rr;
          int col = nt * 128 + cc;
          val = fmaxf(val + bias[node * GH + col], 0.f);
          obf[(size_t)(b_ * NNODE + node) * GH + col] = f2bf(val);
        } else if constexpr (MODE == 1) {
          int R = mt * 128 + rr;
          int col = nt * 128 + cc;
          obf[(size_t)R * GH + col] = f2bf(val);
        } else if constexpr (MODE == 2) {
          int b_ = mt * 128 + rr;
          val = fmaxf(val + bias[node * DH + cc], 0.f);
          obf[(size_t)b_ * (NNODE * DH) + node * DH + cc] = f2bf(val);
        } else {
          int R = mt * 128 + rr;
          if (blockIdx.y == 0) val += bias[cc];
          atomicAdd(&of[R * OUTC + cc], val);
        }
      }
    }
  }
}

extern "C" void kernel_launch(void* const* d_in, const int* in_sizes, int n_in,
                              void* d_out, int out_size, void* d_ws, size_t ws_size,
                              hipStream_t stream) {
  const float* x1 = (const float*)d_in[0];
  const float* x2 = (const float*)d_in[1];
  const int* e1 = (const int*)d_in[2];
  const int* e2 = (const int*)d_in[3];
  const float* w3 = (const float*)d_in[4];  const float* b3 = (const float*)d_in[5];
  const float* w5 = (const float*)d_in[6];  const float* b5 = (const float*)d_in[7];
  const float* w7 = (const float*)d_in[8];  const float* b7 = (const float*)d_in[9];
  const float* Wff = (const float*)d_in[10]; const float* bff = (const float*)d_in[11];
  const float* Wg = (const float*)d_in[12];  const float* bg = (const float*)d_in[13];
  const float* Wd = (const float*)d_in[14];  const float* bd = (const float*)d_in[15];
  const float* Wfc = (const float*)d_in[16]; const float* bfc = (const float*)d_in[17];
  float* out = (float*)d_out;

  char* ws = (char*)d_ws;
  size_t off = 0;
  auto alloc = [&](size_t bytes) -> char* {
    char* p = ws + off;
    off = (off + bytes + 255) & ~(size_t)255;
    return p;
  };
  ushort* Wffb = (ushort*)alloc(19660800ull * 2);
  ushort* Wdb  = (ushort*)alloc(3276800ull * 2);
  ushort* Wfcb = (ushort*)alloc(819200ull * 2);
  ushort* Wgb  = (ushort*)alloc(65536ull * 2);
  ushort* cbuf = (ushort*)alloc(19660800ull * 2);  // per-branch conv output; later aliased as du
  ushort* h1   = (ushort*)alloc(6553600ull * 2);   // later aliased as hg1
  ushort* h2   = (ushort*)alloc(6553600ull * 2);   // later aliased as hg2
  ushort* xw1  = (ushort*)alloc(6553600ull * 2);
  ushort* xw2  = (ushort*)alloc(6553600ull * 2);
  int* deg   = (int*)alloc(2 * NTOT * 4);
  int* offs  = (int*)alloc(2 * (NTOT + 1) * 4 + 8);
  int* curs  = (int*)alloc(2 * NTOT * 4);
  int* csr   = (int*)alloc(2 * NE * 4);
  float* nrm = (float*)alloc(2 * NTOT * 4);
  ushort* du = cbuf;  // alias: cbuf free after branch-2 FF GEMM

  hipMemsetAsync(deg, 0, 2 * NTOT * 4, stream);
  hipMemsetAsync(out, 0, (size_t)out_size * 4, stream);

  cvt_k<<<23264, 256, 0, stream>>>(Wff, Wd, Wfc, Wg, Wffb, Wdb, Wfcb, Wgb);

  // branch 1
  conv_k<<<NTOT, 128, 0, stream>>>(x1, w3, b3, w5, b5, w7, b7, cbuf);
  gemm_k<0><<<dim3(4, 100), 256, 0, stream>>>(cbuf, nullptr, Wffb, h1, nullptr, bff);
  gemm_k<1><<<400, 256, 0, stream>>>(h1, nullptr, Wgb, xw1, nullptr, nullptr);
  // branch 2
  conv_k<<<NTOT, 128, 0, stream>>>(x2, w3, b3, w5, b5, w7, b7, cbuf);
  gemm_k<0><<<dim3(4, 100), 256, 0, stream>>>(cbuf, nullptr, Wffb, h2, nullptr, bff);
  gemm_k<1><<<400, 256, 0, stream>>>(h2, nullptr, Wgb, xw2, nullptr, nullptr);

  // CSR build for both edge sets
  hist_k<<<1600, 256, 0, stream>>>(e1 + NE, deg);
  hist_k<<<1600, 256, 0, stream>>>(e2 + NE, deg + NTOT);
  scan_k<<<1, 1024, 0, stream>>>(deg, offs, curs, nrm);
  scan_k<<<1, 1024, 0, stream>>>(deg + NTOT, offs + NTOT + 1, curs + NTOT, nrm + NTOT);
  fill_k<<<1600, 256, 0, stream>>>(e1, e1 + NE, curs, csr);
  fill_k<<<1600, 256, 0, stream>>>(e2, e2 + NE, curs + NTOT, csr + NE);

  // aggregation (writes hg into h buffers — h no longer needed)
  agg_k<<<6400, 256, 0, stream>>>(xw1, offs, csr, nrm, bg, h1);
  agg_k<<<6400, 256, 0, stream>>>(xw2, offs + NTOT + 1, csr + NE, nrm + NTOT, bg, h2);

  // discrepancy FC + final FC
  gemm_k<2><<<dim3(2, 100), 256, 0, stream>>>(h1, h2, Wdb, du, nullptr, bd);
  gemm_k<3><<<dim3(2, 10), 256, 0, stream>>>(du, nullptr, Wfcb, nullptr, out, bfc);
}

// Round 3
// 367.609 us; speedup vs baseline: 1.2007x; 1.2007x over previous
//
#include <hip/hip_runtime.h>

#define DI __device__ __forceinline__

typedef __bf16 bf16_t;
typedef bf16_t bf16x8 __attribute__((ext_vector_type(8)));
typedef float f32x4 __attribute__((ext_vector_type(4)));
typedef ushort ushort8v __attribute__((ext_vector_type(8)));

static constexpr int NNODE = 100, WIN = 128, GH = 256, DH = 64, OUTC = 128, NB = 256;
static constexpr int NTOT = NB * NNODE;   // 25600
static constexpr int NE = 409600;
static constexpr int FFK = 6 * WIN;       // 768

DI ushort f2bf(float f) {
  union { float f; unsigned u; } v; v.f = f;
  unsigned r = v.u + 0x7fffu + ((v.u >> 16) & 1u);
  return (ushort)(r >> 16);
}
DI float bf2f(ushort s) {
  union { unsigned u; float f; } v; v.u = ((unsigned)s) << 16; return v.f;
}

DI void gload16(const void* g, void* l) {
  __builtin_amdgcn_global_load_lds((const __attribute__((address_space(1))) void*)g,
                                   (__attribute__((address_space(3))) void*)l, 16, 0, 0);
}

// ---------- weight conversion f32 -> bf16 (Wff, Wd, Wfc, Wg) ----------
__global__ void cvt_k(const float* __restrict__ s0, const float* __restrict__ s1,
                      const float* __restrict__ s2, const float* __restrict__ s3,
                      ushort* __restrict__ d0, ushort* __restrict__ d1,
                      ushort* __restrict__ d2, ushort* __restrict__ d3) {
  int j = blockIdx.x * 256 + threadIdx.x;   // vec4 index
  const float* s; ushort* d;
  if (j < 19660800 / 4) { s = s0; d = d0; }
  else if ((j -= 19660800 / 4) < 3276800 / 4) { s = s1; d = d1; }
  else if ((j -= 3276800 / 4) < 819200 / 4) { s = s2; d = d2; }
  else { j -= 819200 / 4; s = s3; d = d3; }
  float4 v = reinterpret_cast<const float4*>(s)[j];
  ushort4 o;
  o.x = f2bf(v.x); o.y = f2bf(v.y); o.z = f2bf(v.z); o.w = f2bf(v.w);
  reinterpret_cast<ushort4*>(d)[j] = o;
}

// ---------- multiscale conv (per node, 1->2ch, k=3/5/7, same pad) + relu -> c bf16 ----------
__global__ __launch_bounds__(128) void conv_k(
    const float* __restrict__ x,
    const float* __restrict__ w3, const float* __restrict__ b3,
    const float* __restrict__ w5, const float* __restrict__ b5,
    const float* __restrict__ w7, const float* __restrict__ b7,
    ushort* __restrict__ c) {
  int r = blockIdx.x;                 // r = b*100 + node
  int b = r / 100, node = r - b * 100;
  __shared__ float xs[136];
  int w = threadIdx.x;
  xs[4 + w] = x[r * WIN + w];
  if (w < 4) { xs[w] = 0.f; xs[132 + w] = 0.f; }
  __syncthreads();
  float v[7];
#pragma unroll
  for (int j = 0; j < 7; ++j) v[j] = xs[1 + w + j];   // x[w-3+j]
  const float* W3 = w3 + node * 6;  const float* B3 = b3 + node * 2;
  const float* W5 = w5 + node * 10; const float* B5 = b5 + node * 2;
  const float* W7 = w7 + node * 14; const float* B7 = b7 + node * 2;
  ushort* out = c + (size_t)(node * NB + b) * FFK + w;
#pragma unroll
  for (int ch = 0; ch < 2; ++ch) {
    float a3 = B3[ch], a5 = B5[ch], a7 = B7[ch];
#pragma unroll
    for (int j = 0; j < 3; ++j) a3 += W3[ch * 3 + j] * v[2 + j];
#pragma unroll
    for (int j = 0; j < 5; ++j) a5 += W5[ch * 5 + j] * v[1 + j];
#pragma unroll
    for (int j = 0; j < 7; ++j) a7 += W7[ch * 7 + j] * v[j];
    out[(0 + ch) * WIN] = f2bf(fmaxf(a3, 0.f));
    out[(2 + ch) * WIN] = f2bf(fmaxf(a5, 0.f));
    out[(4 + ch) * WIN] = f2bf(fmaxf(a7, 0.f));
  }
}

// ---------- degree histogram ----------
__global__ void hist_k(const int* __restrict__ dst, int* __restrict__ deg) {
  int i = blockIdx.x * 256 + threadIdx.x;
  if (i < NE) atomicAdd(&deg[dst[i]], 1);
}

// ---------- single-block scan: offs/cursor/norm ----------
__global__ __launch_bounds__(1024) void scan_k(const int* __restrict__ deg, int* __restrict__ offs,
                                               int* __restrict__ cursor, float* __restrict__ norm) {
  __shared__ int part[1024];
  int t = threadIdx.x;
  int base = t * 25;
  int local[25];
  int s = 0;
#pragma unroll
  for (int j = 0; j < 25; ++j) { local[j] = s; s += deg[base + j]; }
  part[t] = s;
  __syncthreads();
  for (int d = 1; d < 1024; d <<= 1) {
    int vv = (t >= d) ? part[t - d] : 0;
    __syncthreads();
    part[t] += vv;
    __syncthreads();
  }
  int excl = (t > 0) ? part[t - 1] : 0;
#pragma unroll
  for (int j = 0; j < 25; ++j) {
    int o = excl + local[j];
    offs[base + j] = o;
    cursor[base + j] = o;
    norm[base + j] = rsqrtf((float)(deg[base + j] + 1));   // +1 self loop
  }
  if (t == 1023) offs[NTOT] = part[1023];
}

// ---------- CSR fill ----------
__global__ void fill_k(const int* __restrict__ src, const int* __restrict__ dst,
                       int* __restrict__ cursor, int* __restrict__ csr) {
  int i = blockIdx.x * 256 + threadIdx.x;
  if (i < NE) {
    int d = dst[i];
    int pos = atomicAdd(&cursor[d], 1);
    csr[pos] = src[i];
  }
}

// ---------- GCN aggregation: one wave per dst node, 2 half-wave edge streams, 4-deep unroll ----------
// xw rows are PRE-SCALED by norm[src] (done in gemm_k<1> epilogue).
// hg[v] = relu(norm[v] * (xw'[v] + sum_j xw'[csr[j]]) + bg)
__global__ __launch_bounds__(256) void agg_k(const ushort* __restrict__ xw, const int* __restrict__ offs,
                                             const int* __restrict__ csr, const float* __restrict__ norm,
                                             const float* __restrict__ bg, ushort* __restrict__ hg) {
  int v = blockIdx.x * 4 + (threadIdx.x >> 6);
  int lane = threadIdx.x & 63;
  int half = lane >> 5;
  int colb = (lane & 31) * 8;           // 8 bf16 per lane, 32 lanes cover the 256-wide row
  const ushort* base = xw + colb;

  float a[8] = {0.f, 0.f, 0.f, 0.f, 0.f, 0.f, 0.f, 0.f};
  if (half == 0) {                       // self loop (once)
    ushort8v q = *reinterpret_cast<const ushort8v*>(base + (size_t)v * GH);
#pragma unroll
    for (int i = 0; i < 8; ++i) a[i] += bf2f(q[i]);
  }
  int e0 = offs[v], e1 = offs[v + 1];
  int j = e0 + half;                     // this half owns edges at stride 2
  // 4-deep unroll: 4 independent gathers in flight per half (8 per wave)
  for (; j + 6 < e1; j += 8) {
    int s0 = csr[j], s1 = csr[j + 2], s2 = csr[j + 4], s3 = csr[j + 6];
    ushort8v q0 = *reinterpret_cast<const ushort8v*>(base + (size_t)s0 * GH);
    ushort8v q1 = *reinterpret_cast<const ushort8v*>(base + (size_t)s1 * GH);
    ushort8v q2 = *reinterpret_cast<const ushort8v*>(base + (size_t)s2 * GH);
    ushort8v q3 = *reinterpret_cast<const ushort8v*>(base + (size_t)s3 * GH);
#pragma unroll
    for (int i = 0; i < 8; ++i)
      a[i] += (bf2f(q0[i]) + bf2f(q1[i])) + (bf2f(q2[i]) + bf2f(q3[i]));
  }
  for (; j + 2 < e1; j += 4) {
    int s0 = csr[j], s1 = csr[j + 2];
    ushort8v q0 = *reinterpret_cast<const ushort8v*>(base + (size_t)s0 * GH);
    ushort8v q1 = *reinterpret_cast<const ushort8v*>(base + (size_t)s1 * GH);
#pragma unroll
    for (int i = 0; i < 8; ++i) a[i] += bf2f(q0[i]) + bf2f(q1[i]);
  }
  if (j < e1) {
    int s0 = csr[j];
    ushort8v q0 = *reinterpret_cast<const ushort8v*>(base + (size_t)s0 * GH);
#pragma unroll
    for (int i = 0; i < 8; ++i) a[i] += bf2f(q0[i]);
  }
  // combine the two half-wave streams
#pragma unroll
  for (int i = 0; i < 8; ++i) a[i] += __shfl_xor(a[i], 32);

  if (half == 0) {
    float nv = norm[v];
    float4 bb0 = *reinterpret_cast<const float4*>(bg + colb);
    float4 bb1 = *reinterpret_cast<const float4*>(bg + colb + 4);
    ushort8v o;
    o[0] = f2bf(fmaxf(nv * a[0] + bb0.x, 0.f));
    o[1] = f2bf(fmaxf(nv * a[1] + bb0.y, 0.f));
    o[2] = f2bf(fmaxf(nv * a[2] + bb0.z, 0.f));
    o[3] = f2bf(fmaxf(nv * a[3] + bb0.w, 0.f));
    o[4] = f2bf(fmaxf(nv * a[4] + bb1.x, 0.f));
    o[5] = f2bf(fmaxf(nv * a[5] + bb1.y, 0.f));
    o[6] = f2bf(fmaxf(nv * a[6] + bb1.z, 0.f));
    o[7] = f2bf(fmaxf(nv * a[7] + bb1.w, 0.f));
    *reinterpret_cast<ushort8v*>(hg + (size_t)v * GH + colb) = o;
  }
}

// ---------- BT GEMM, 128xBN tile, BK=64, global_load_lds staging ----------
// MODE 0: h[b*100+node] = relu(c[node] @ Wff[node]^T + bff[node])   M=256/node, N=256, K=768
// MODE 1: xw'[R] = nrm[R] * (h @ Wg^T)[R]                           M=25600, N=256, K=256
// MODE 2: du[b][node*64+] = relu(cat(h1g,h2g) @ Wd[node]^T + bd)    M=256/node, N=64, K=512
// MODE 3: out += du @ Wfc^T (+bfc on ks==0), K-split atomics        M=256, N=128, K=6400
template <int MODE>
__global__ __launch_bounds__(256) void gemm_k(const ushort* __restrict__ A, const ushort* __restrict__ A2,
                                              const ushort* __restrict__ Bm, ushort* __restrict__ obf,
                                              float* __restrict__ of, const float* __restrict__ bias) {
  constexpr int BN = (MODE == 2) ? 64 : 128;
  constexpr int KT = (MODE == 0) ? 12 : (MODE == 1) ? 4 : (MODE == 2) ? 8 : 4;
  constexpr int LDA = (MODE == 0) ? 768 : (MODE == 1) ? 256 : (MODE == 2) ? 256 : 6400;
  constexpr int LDB = (MODE == 0) ? 768 : (MODE == 1) ? 256 : (MODE == 2) ? 512 : 6400;
  constexpr int MF = (MODE == 2) ? 2 : 4;
  constexpr int NF = 4;

  __shared__ ushort As[128 * 64];
  __shared__ ushort Bs[BN * 64];

  const int tid = threadIdx.x, wv = tid >> 6, lane = tid & 63;

  int mt = 0, nt = 0, node = 0, kbase = 0;
  if constexpr (MODE == 0) { mt = blockIdx.x >> 1; nt = blockIdx.x & 1; node = blockIdx.y; }
  else if constexpr (MODE == 1) { mt = blockIdx.x >> 1; nt = blockIdx.x & 1; }
  else if constexpr (MODE == 2) { mt = blockIdx.x; node = blockIdx.y; }
  else { mt = blockIdx.x; kbase = blockIdx.y * 256; }

  const ushort* Ab = nullptr; const ushort* Bb = nullptr;
  if constexpr (MODE == 0) { Ab = A + (size_t)node * (NB * FFK) + (size_t)mt * 128 * FFK;
                             Bb = Bm + (size_t)node * (GH * FFK) + (size_t)nt * 128 * FFK; }
  else if constexpr (MODE == 1) { Ab = A + (size_t)mt * 128 * GH; Bb = Bm + (size_t)nt * 128 * GH; }
  else if constexpr (MODE == 2) { Bb = Bm + (size_t)node * (DH * 512); }
  else { Ab = A + (size_t)mt * 128 * 6400 + kbase; Bb = Bm + kbase; }

  const int wr = (MODE == 2) ? wv : (wv >> 1);
  const int wc = (MODE == 2) ? 0 : (wv & 1);

  f32x4 acc[MF][NF] = {};

  for (int kt = 0; kt < KT; ++kt) {
    const int k0 = kt * 64;
    __syncthreads();
#pragma unroll
    for (int it = 0; it < 4; ++it) {
      int rb = it * 32 + wv * 8;
      int row = rb + (lane >> 3);
      const ushort* gp;
      if constexpr (MODE == 2) {
        int b_ = mt * 128 + row;
        const ushort* src = (k0 < 256) ? A : A2;
        gp = src + (size_t)(b_ * NNODE + node) * GH + (k0 & 255) + (lane & 7) * 8;
      } else {
        gp = Ab + (size_t)row * LDA + k0 + (lane & 7) * 8;
      }
      gload16(gp, &As[rb * 64]);
    }
#pragma unroll
    for (int it = 0; it < BN / 32; ++it) {
      int rb = it * 32 + wv * 8;
      int row = rb + (lane >> 3);
      gload16(Bb + (size_t)row * LDB + k0 + (lane & 7) * 8, &Bs[rb * 64]);
    }
    __syncthreads();
#pragma unroll
    for (int kk = 0; kk < 2; ++kk) {
      bf16x8 af[MF], bfr[NF];
#pragma unroll
      for (int m = 0; m < MF; ++m) {
        int rr = wr * (MF * 16) + m * 16 + (lane & 15);
        af[m] = *reinterpret_cast<const bf16x8*>(&As[rr * 64 + kk * 32 + (lane >> 4) * 8]);
      }
#pragma unroll
      for (int n = 0; n < NF; ++n) {
        int rr = wc * 64 + n * 16 + (lane & 15);
        bfr[n] = *reinterpret_cast<const bf16x8*>(&Bs[rr * 64 + kk * 32 + (lane >> 4) * 8]);
      }
#pragma unroll
      for (int m = 0; m < MF; ++m)
#pragma unroll
        for (int n = 0; n < NF; ++n)
          acc[m][n] = __builtin_amdgcn_mfma_f32_16x16x32_bf16(af[m], bfr[n], acc[m][n], 0, 0, 0);
    }
  }

  const int lrow = (lane >> 4) * 4, lcol = lane & 15;
#pragma unroll
  for (int m = 0; m < MF; ++m) {
#pragma unroll
    for (int n = 0; n < NF; ++n) {
      int cc = wc * 64 + n * 16 + lcol;
#pragma unroll
      for (int rg = 0; rg < 4; ++rg) {
        int rr = wr * (MF * 16) + m * 16 + lrow + rg;
        float val = acc[m][n][rg];
        if constexpr (MODE == 0) {
          int b_ = mt * 128 + rr;
          int col = nt * 128 + cc;
          val = fmaxf(val + bias[node * GH + col], 0.f);
          obf[(size_t)(b_ * NNODE + node) * GH + col] = f2bf(val);
        } else if constexpr (MODE == 1) {
          int R = mt * 128 + rr;
          int col = nt * 128 + cc;
          obf[(size_t)R * GH + col] = f2bf(val * bias[R]);   // pre-scale by norm[R]
        } else if constexpr (MODE == 2) {
          int b_ = mt * 128 + rr;
          val = fmaxf(val + bias[node * DH + cc], 0.f);
          obf[(size_t)b_ * (NNODE * DH) + node * DH + cc] = f2bf(val);
        } else {
          int R = mt * 128 + rr;
          if (blockIdx.y == 0) val += bias[cc];
          atomicAdd(&of[R * OUTC + cc], val);
        }
      }
    }
  }
}

extern "C" void kernel_launch(void* const* d_in, const int* in_sizes, int n_in,
                              void* d_out, int out_size, void* d_ws, size_t ws_size,
                              hipStream_t stream) {
  const float* x1 = (const float*)d_in[0];
  const float* x2 = (const float*)d_in[1];
  const int* e1 = (const int*)d_in[2];
  const int* e2 = (const int*)d_in[3];
  const float* w3 = (const float*)d_in[4];  const float* b3 = (const float*)d_in[5];
  const float* w5 = (const float*)d_in[6];  const float* b5 = (const float*)d_in[7];
  const float* w7 = (const float*)d_in[8];  const float* b7 = (const float*)d_in[9];
  const float* Wff = (const float*)d_in[10]; const float* bff = (const float*)d_in[11];
  const float* Wg = (const float*)d_in[12];  const float* bg = (const float*)d_in[13];
  const float* Wd = (const float*)d_in[14];  const float* bd = (const float*)d_in[15];
  const float* Wfc = (const float*)d_in[16]; const float* bfc = (const float*)d_in[17];
  float* out = (float*)d_out;

  char* ws = (char*)d_ws;
  size_t off = 0;
  auto alloc = [&](size_t bytes) -> char* {
    char* p = ws + off;
    off = (off + bytes + 255) & ~(size_t)255;
    return p;
  };
  ushort* Wffb = (ushort*)alloc(19660800ull * 2);
  ushort* Wdb  = (ushort*)alloc(3276800ull * 2);
  ushort* Wfcb = (ushort*)alloc(819200ull * 2);
  ushort* Wgb  = (ushort*)alloc(65536ull * 2);
  ushort* cbuf = (ushort*)alloc(19660800ull * 2);  // per-branch conv output; later aliased as du
  ushort* h1   = (ushort*)alloc(6553600ull * 2);   // later aliased as hg1
  ushort* h2   = (ushort*)alloc(6553600ull * 2);   // later aliased as hg2
  ushort* xw1  = (ushort*)alloc(6553600ull * 2);
  ushort* xw2  = (ushort*)alloc(6553600ull * 2);
  int* deg   = (int*)alloc(2 * NTOT * 4);
  int* offs  = (int*)alloc(2 * (NTOT + 1) * 4 + 8);
  int* curs  = (int*)alloc(2 * NTOT * 4);
  int* csr   = (int*)alloc(2 * NE * 4);
  float* nrm = (float*)alloc(2 * NTOT * 4);
  ushort* du = cbuf;  // alias: cbuf free after branch-2 FF GEMM

  hipMemsetAsync(deg, 0, 2 * NTOT * 4, stream);
  hipMemsetAsync(out, 0, (size_t)out_size * 4, stream);

  cvt_k<<<23264, 256, 0, stream>>>(Wff, Wd, Wfc, Wg, Wffb, Wdb, Wfcb, Wgb);

  // CSR build first (independent of conv/GEMMs; nrm needed by gemm_k<1>)
  hist_k<<<1600, 256, 0, stream>>>(e1 + NE, deg);
  hist_k<<<1600, 256, 0, stream>>>(e2 + NE, deg + NTOT);
  scan_k<<<1, 1024, 0, stream>>>(deg, offs, curs, nrm);
  scan_k<<<1, 1024, 0, stream>>>(deg + NTOT, offs + NTOT + 1, curs + NTOT, nrm + NTOT);
  fill_k<<<1600, 256, 0, stream>>>(e1, e1 + NE, curs, csr);
  fill_k<<<1600, 256, 0, stream>>>(e2, e2 + NE, curs + NTOT, csr + NE);

  // branch 1
  conv_k<<<NTOT, 128, 0, stream>>>(x1, w3, b3, w5, b5, w7, b7, cbuf);
  gemm_k<0><<<dim3(4, 100), 256, 0, stream>>>(cbuf, nullptr, Wffb, h1, nullptr, bff);
  gemm_k<1><<<400, 256, 0, stream>>>(h1, nullptr, Wgb, xw1, nullptr, nrm);
  // branch 2
  conv_k<<<NTOT, 128, 0, stream>>>(x2, w3, b3, w5, b5, w7, b7, cbuf);
  gemm_k<0><<<dim3(4, 100), 256, 0, stream>>>(cbuf, nullptr, Wffb, h2, nullptr, bff);
  gemm_k<1><<<400, 256, 0, stream>>>(h2, nullptr, Wgb, xw2, nullptr, nrm + NTOT);

  // aggregation (writes hg into h buffers — h no longer needed)
  agg_k<<<6400, 256, 0, stream>>>(xw1, offs, csr, nrm, bg, h1);
  agg_k<<<6400, 256, 0, stream>>>(xw2, offs + NTOT + 1, csr + NE, nrm + NTOT, bg, h2);

  // discrepancy FC + final FC
  gemm_k<2><<<dim3(2, 100), 256, 0, stream>>>(h1, h2, Wdb, du, nullptr, bd);
  gemm_k<3><<<dim3(2, 25), 256, 0, stream>>>(du, nullptr, Wfcb, nullptr, out, bfc);
}

// Round 4
// 361.158 us; speedup vs baseline: 1.2221x; 1.0179x over previous
//
#include <hip/hip_runtime.h>

#define DI __device__ __forceinline__

typedef __bf16 bf16_t;
typedef bf16_t bf16x8 __attribute__((ext_vector_type(8)));
typedef float f32x4 __attribute__((ext_vector_type(4)));
typedef ushort ushort8v __attribute__((ext_vector_type(8)));

static constexpr int NNODE = 100, WIN = 128, GH = 256, DH = 64, OUTC = 128, NB = 256;
static constexpr int NTOT = NB * NNODE;   // 25600
static constexpr int NE = 409600;
static constexpr int FFK = 6 * WIN;       // 768
static constexpr size_t CB = (size_t)NNODE * NB * FFK;   // per-branch conv buf elems (19,660,800)
static constexpr size_t HB = (size_t)NTOT * GH;          // per-branch h/xw elems (6,553,600)

DI ushort f2bf(float f) {
  union { float f; unsigned u; } v; v.f = f;
  unsigned r = v.u + 0x7fffu + ((v.u >> 16) & 1u);
  return (ushort)(r >> 16);
}
DI float bf2f(ushort s) {
  union { unsigned u; float f; } v; v.u = ((unsigned)s) << 16; return v.f;
}

DI void gload16(const void* g, void* l) {
  __builtin_amdgcn_global_load_lds((const __attribute__((address_space(1))) void*)g,
                                   (__attribute__((address_space(3))) void*)l, 16, 0, 0);
}

// ---------- weight conversion f32 -> bf16 (Wff, Wd, Wfc, Wg) ----------
__global__ void cvt_k(const float* __restrict__ s0, const float* __restrict__ s1,
                      const float* __restrict__ s2, const float* __restrict__ s3,
                      ushort* __restrict__ d0, ushort* __restrict__ d1,
                      ushort* __restrict__ d2, ushort* __restrict__ d3) {
  int j = blockIdx.x * 256 + threadIdx.x;   // vec4 index
  const float* s; ushort* d;
  if (j < 19660800 / 4) { s = s0; d = d0; }
  else if ((j -= 19660800 / 4) < 3276800 / 4) { s = s1; d = d1; }
  else if ((j -= 3276800 / 4) < 819200 / 4) { s = s2; d = d2; }
  else { j -= 819200 / 4; s = s3; d = d3; }
  float4 v = reinterpret_cast<const float4*>(s)[j];
  ushort4 o;
  o.x = f2bf(v.x); o.y = f2bf(v.y); o.z = f2bf(v.z); o.w = f2bf(v.w);
  reinterpret_cast<ushort4*>(d)[j] = o;
}

// ---------- multiscale conv, BOTH branches; 2 rows per 256-thread block ----------
__global__ __launch_bounds__(256) void conv_k(
    const float* __restrict__ x1, const float* __restrict__ x2,
    const float* __restrict__ w3, const float* __restrict__ b3,
    const float* __restrict__ w5, const float* __restrict__ b5,
    const float* __restrict__ w7, const float* __restrict__ b7,
    ushort* __restrict__ c) {
  int r = blockIdx.x * 2 + (threadIdx.x >> 7);   // [0, 51200)
  int w = threadIdx.x & 127;
  int half = threadIdx.x >> 7;
  int br = r >= NTOT;
  int rr = r - br * NTOT;
  const float* x = br ? x2 : x1;
  int b = rr / 100, node = rr - b * 100;
  __shared__ float xs[2][136];
  xs[half][4 + w] = x[rr * WIN + w];
  if (w < 4) { xs[half][w] = 0.f; xs[half][132 + w] = 0.f; }
  __syncthreads();
  float v[7];
#pragma unroll
  for (int j = 0; j < 7; ++j) v[j] = xs[half][1 + w + j];   // x[w-3+j]
  const float* W3 = w3 + node * 6;  const float* B3 = b3 + node * 2;
  const float* W5 = w5 + node * 10; const float* B5 = b5 + node * 2;
  const float* W7 = w7 + node * 14; const float* B7 = b7 + node * 2;
  ushort* out = c + (size_t)br * CB + (size_t)(node * NB + b) * FFK + w;
#pragma unroll
  for (int ch = 0; ch < 2; ++ch) {
    float a3 = B3[ch], a5 = B5[ch], a7 = B7[ch];
#pragma unroll
    for (int j = 0; j < 3; ++j) a3 += W3[ch * 3 + j] * v[2 + j];
#pragma unroll
    for (int j = 0; j < 5; ++j) a5 += W5[ch * 5 + j] * v[1 + j];
#pragma unroll
    for (int j = 0; j < 7; ++j) a7 += W7[ch * 7 + j] * v[j];
    out[(0 + ch) * WIN] = f2bf(fmaxf(a3, 0.f));
    out[(2 + ch) * WIN] = f2bf(fmaxf(a5, 0.f));
    out[(4 + ch) * WIN] = f2bf(fmaxf(a7, 0.f));
  }
}

// ---------- degree histogram, both edge sets ----------
__global__ void hist_k(const int* __restrict__ d1, const int* __restrict__ d2,
                       int* __restrict__ deg) {
  int i = blockIdx.x * 256 + threadIdx.x;
  if (i < NE) atomicAdd(&deg[d1[i]], 1);
  else if (i < 2 * NE) atomicAdd(&deg[NTOT + d2[i - NE]], 1);
}

// ---------- 2-block scan: offs/cursor/norm, one block per edge set ----------
__global__ __launch_bounds__(1024) void scan_k(const int* __restrict__ deg_, int* __restrict__ offs_,
                                               int* __restrict__ cursor_, float* __restrict__ norm_) {
  int set = blockIdx.x;
  const int* deg = deg_ + set * NTOT;
  int* offs = offs_ + set * (NTOT + 1);
  int* cursor = cursor_ + set * NTOT;
  float* norm = norm_ + set * NTOT;
  __shared__ int part[1024];
  int t = threadIdx.x;
  int base = t * 25;
  int local[25];
  int s = 0;
#pragma unroll
  for (int j = 0; j < 25; ++j) { local[j] = s; s += deg[base + j]; }
  part[t] = s;
  __syncthreads();
  for (int d = 1; d < 1024; d <<= 1) {
    int vv = (t >= d) ? part[t - d] : 0;
    __syncthreads();
    part[t] += vv;
    __syncthreads();
  }
  int excl = (t > 0) ? part[t - 1] : 0;
#pragma unroll
  for (int j = 0; j < 25; ++j) {
    int o = excl + local[j];
    offs[base + j] = o;
    cursor[base + j] = o;
    norm[base + j] = rsqrtf((float)(deg[base + j] + 1));   // +1 self loop
  }
  if (t == 1023) offs[NTOT] = part[1023];
}

// ---------- CSR fill, both edge sets ----------
__global__ void fill_k(const int* __restrict__ e1, const int* __restrict__ e2,
                       int* __restrict__ cursor, int* __restrict__ csr) {
  int i = blockIdx.x * 256 + threadIdx.x;
  if (i < NE) {
    int d = e1[NE + i];
    int pos = atomicAdd(&cursor[d], 1);
    csr[pos] = e1[i];
  } else if (i < 2 * NE) {
    int d = e2[NE + i - NE];
    int pos = atomicAdd(&cursor[NTOT + d], 1);
    csr[NE + pos] = e2[i - NE];
  }
}

// ---------- GCN aggregation, both branches: one wave per dst node ----------
// xw rows PRE-SCALED by norm[src]; hg[v] = relu(norm[v]*(xw'[v]+sum xw'[csr[j]]) + bg)
__global__ __launch_bounds__(256) void agg_k(const ushort* __restrict__ xw_, const int* __restrict__ offs_,
                                             const int* __restrict__ csr_, const float* __restrict__ norm_,
                                             const float* __restrict__ bg, ushort* __restrict__ hg_) {
  int idx = blockIdx.x * 4 + (threadIdx.x >> 6);   // [0, 51200)
  int br = idx >= NTOT;
  int v = idx - br * NTOT;
  const ushort* xw = xw_ + (size_t)br * HB;
  const int* offs = offs_ + br * (NTOT + 1);
  const int* csr = csr_ + br * NE;
  const float* norm = norm_ + br * NTOT;
  ushort* hg = hg_ + (size_t)br * HB;

  int lane = threadIdx.x & 63;
  int half = lane >> 5;
  int colb = (lane & 31) * 8;           // 8 bf16 per lane, 32 lanes cover the 256-wide row
  const ushort* base = xw + colb;

  float a[8] = {0.f, 0.f, 0.f, 0.f, 0.f, 0.f, 0.f, 0.f};
  if (half == 0) {                       // self loop (once)
    ushort8v q = *reinterpret_cast<const ushort8v*>(base + (size_t)v * GH);
#pragma unroll
    for (int i = 0; i < 8; ++i) a[i] += bf2f(q[i]);
  }
  int e0 = offs[v], e1 = offs[v + 1];
  int j = e0 + half;                     // this half owns edges at stride 2
  for (; j + 6 < e1; j += 8) {
    int s0 = csr[j], s1 = csr[j + 2], s2 = csr[j + 4], s3 = csr[j + 6];
    ushort8v q0 = *reinterpret_cast<const ushort8v*>(base + (size_t)s0 * GH);
    ushort8v q1 = *reinterpret_cast<const ushort8v*>(base + (size_t)s1 * GH);
    ushort8v q2 = *reinterpret_cast<const ushort8v*>(base + (size_t)s2 * GH);
    ushort8v q3 = *reinterpret_cast<const ushort8v*>(base + (size_t)s3 * GH);
#pragma unroll
    for (int i = 0; i < 8; ++i)
      a[i] += (bf2f(q0[i]) + bf2f(q1[i])) + (bf2f(q2[i]) + bf2f(q3[i]));
  }
  for (; j + 2 < e1; j += 4) {
    int s0 = csr[j], s1 = csr[j + 2];
    ushort8v q0 = *reinterpret_cast<const ushort8v*>(base + (size_t)s0 * GH);
    ushort8v q1 = *reinterpret_cast<const ushort8v*>(base + (size_t)s1 * GH);
#pragma unroll
    for (int i = 0; i < 8; ++i) a[i] += bf2f(q0[i]) + bf2f(q1[i]);
  }
  if (j < e1) {
    int s0 = csr[j];
    ushort8v q0 = *reinterpret_cast<const ushort8v*>(base + (size_t)s0 * GH);
#pragma unroll
    for (int i = 0; i < 8; ++i) a[i] += bf2f(q0[i]);
  }
#pragma unroll
  for (int i = 0; i < 8; ++i) a[i] += __shfl_xor(a[i], 32);

  if (half == 0) {
    float nv = norm[v];
    float4 bb0 = *reinterpret_cast<const float4*>(bg + colb);
    float4 bb1 = *reinterpret_cast<const float4*>(bg + colb + 4);
    ushort8v o;
    o[0] = f2bf(fmaxf(nv * a[0] + bb0.x, 0.f));
    o[1] = f2bf(fmaxf(nv * a[1] + bb0.y, 0.f));
    o[2] = f2bf(fmaxf(nv * a[2] + bb0.z, 0.f));
    o[3] = f2bf(fmaxf(nv * a[3] + bb0.w, 0.f));
    o[4] = f2bf(fmaxf(nv * a[4] + bb1.x, 0.f));
    o[5] = f2bf(fmaxf(nv * a[5] + bb1.y, 0.f));
    o[6] = f2bf(fmaxf(nv * a[6] + bb1.z, 0.f));
    o[7] = f2bf(fmaxf(nv * a[7] + bb1.w, 0.f));
    *reinterpret_cast<ushort8v*>(hg + (size_t)v * GH + colb) = o;
  }
}

// ---------- BT GEMM, 128xBN tile, BK=64, global_load_lds staging ----------
// MODE 0 (both branches): h = relu(c @ Wff[node]^T + bff[node])   grid (4, 200)
// MODE 1 (both branches): xw' = nrm * (h @ Wg^T)                  grid 800
// MODE 2: du = relu(cat(hg1,hg2) @ Wd[node]^T + bd)               grid (2, 100)
// MODE 3: out += du @ Wfc^T (+bfc on y==0), K-split atomics       grid (2, 25)
template <int MODE>
__global__ __launch_bounds__(256) void gemm_k(const ushort* __restrict__ A, const ushort* __restrict__ A2,
                                              const ushort* __restrict__ Bm, ushort* __restrict__ obf,
                                              float* __restrict__ of, const float* __restrict__ bias) {
  constexpr int BN = (MODE == 2) ? 64 : 128;
  constexpr int KT = (MODE == 0) ? 12 : (MODE == 1) ? 4 : (MODE == 2) ? 8 : 4;
  constexpr int LDA = (MODE == 0) ? 768 : (MODE == 1) ? 256 : (MODE == 2) ? 256 : 6400;
  constexpr int LDB = (MODE == 0) ? 768 : (MODE == 1) ? 256 : (MODE == 2) ? 512 : 6400;
  constexpr int MF = (MODE == 2) ? 2 : 4;
  constexpr int NF = 4;

  __shared__ ushort As[128 * 64];
  __shared__ ushort Bs[BN * 64];

  const int tid = threadIdx.x, wv = tid >> 6, lane = tid & 63;

  int mt = 0, nt = 0, node = 0, kbase = 0, br = 0;
  if constexpr (MODE == 0) { mt = blockIdx.x >> 1; nt = blockIdx.x & 1;
                             br = blockIdx.y >= 100; node = blockIdx.y - br * 100; }
  else if constexpr (MODE == 1) { int bx = blockIdx.x; br = bx >= 400; bx -= br * 400;
                                  mt = bx >> 1; nt = bx & 1; }
  else if constexpr (MODE == 2) { mt = blockIdx.x; node = blockIdx.y; }
  else { mt = blockIdx.x; kbase = blockIdx.y * 256; }

  const ushort* Ab = nullptr; const ushort* Bb = nullptr;
  if constexpr (MODE == 0) { Ab = A + (size_t)br * CB + (size_t)node * (NB * FFK) + (size_t)mt * 128 * FFK;
                             Bb = Bm + (size_t)node * (GH * FFK) + (size_t)nt * 128 * FFK; }
  else if constexpr (MODE == 1) { Ab = A + (size_t)br * HB + (size_t)mt * 128 * GH;
                                  Bb = Bm + (size_t)nt * 128 * GH; }
  else if constexpr (MODE == 2) { Bb = Bm + (size_t)node * (DH * 512); }
  else { Ab = A + (size_t)mt * 128 * 6400 + kbase; Bb = Bm + kbase; }

  const int wr = (MODE == 2) ? wv : (wv >> 1);
  const int wc = (MODE == 2) ? 0 : (wv & 1);

  f32x4 acc[MF][NF] = {};

  for (int kt = 0; kt < KT; ++kt) {
    const int k0 = kt * 64;
    __syncthreads();
#pragma unroll
    for (int it = 0; it < 4; ++it) {
      int rb = it * 32 + wv * 8;
      int row = rb + (lane >> 3);
      const ushort* gp;
      if constexpr (MODE == 2) {
        int b_ = mt * 128 + row;
        const ushort* src = (k0 < 256) ? A : A2;
        gp = src + (size_t)(b_ * NNODE + node) * GH + (k0 & 255) + (lane & 7) * 8;
      } else {
        gp = Ab + (size_t)row * LDA + k0 + (lane & 7) * 8;
      }
      gload16(gp, &As[rb * 64]);
    }
#pragma unroll
    for (int it = 0; it < BN / 32; ++it) {
      int rb = it * 32 + wv * 8;
      int row = rb + (lane >> 3);
      gload16(Bb + (size_t)row * LDB + k0 + (lane & 7) * 8, &Bs[rb * 64]);
    }
    __syncthreads();
#pragma unroll
    for (int kk = 0; kk < 2; ++kk) {
      bf16x8 af[MF], bfr[NF];
#pragma unroll
      for (int m = 0; m < MF; ++m) {
        int rr = wr * (MF * 16) + m * 16 + (lane & 15);
        af[m] = *reinterpret_cast<const bf16x8*>(&As[rr * 64 + kk * 32 + (lane >> 4) * 8]);
      }
#pragma unroll
      for (int n = 0; n < NF; ++n) {
        int rr = wc * 64 + n * 16 + (lane & 15);
        bfr[n] = *reinterpret_cast<const bf16x8*>(&Bs[rr * 64 + kk * 32 + (lane >> 4) * 8]);
      }
#pragma unroll
      for (int m = 0; m < MF; ++m)
#pragma unroll
        for (int n = 0; n < NF; ++n)
          acc[m][n] = __builtin_amdgcn_mfma_f32_16x16x32_bf16(af[m], bfr[n], acc[m][n], 0, 0, 0);
    }
  }

  const int lrow = (lane >> 4) * 4, lcol = lane & 15;
#pragma unroll
  for (int m = 0; m < MF; ++m) {
#pragma unroll
    for (int n = 0; n < NF; ++n) {
      int cc = wc * 64 + n * 16 + lcol;
#pragma unroll
      for (int rg = 0; rg < 4; ++rg) {
        int rr = wr * (MF * 16) + m * 16 + lrow + rg;
        float val = acc[m][n][rg];
        if constexpr (MODE == 0) {
          int b_ = mt * 128 + rr;
          int col = nt * 128 + cc;
          val = fmaxf(val + bias[node * GH + col], 0.f);
          obf[(size_t)br * HB + (size_t)(b_ * NNODE + node) * GH + col] = f2bf(val);
        } else if constexpr (MODE == 1) {
          int R = mt * 128 + rr;
          int col = nt * 128 + cc;
          obf[(size_t)br * HB + (size_t)R * GH + col] = f2bf(val * bias[br * NTOT + R]);
        } else if constexpr (MODE == 2) {
          int b_ = mt * 128 + rr;
          val = fmaxf(val + bias[node * DH + cc], 0.f);
          obf[(size_t)b_ * (NNODE * DH) + node * DH + cc] = f2bf(val);
        } else {
          int R = mt * 128 + rr;
          if (blockIdx.y == 0) val += bias[cc];
          atomicAdd(&of[R * OUTC + cc], val);
        }
      }
    }
  }
}

extern "C" void kernel_launch(void* const* d_in, const int* in_sizes, int n_in,
                              void* d_out, int out_size, void* d_ws, size_t ws_size,
                              hipStream_t stream) {
  const float* x1 = (const float*)d_in[0];
  const float* x2 = (const float*)d_in[1];
  const int* e1 = (const int*)d_in[2];
  const int* e2 = (const int*)d_in[3];
  const float* w3 = (const float*)d_in[4];  const float* b3 = (const float*)d_in[5];
  const float* w5 = (const float*)d_in[6];  const float* b5 = (const float*)d_in[7];
  const float* w7 = (const float*)d_in[8];  const float* b7 = (const float*)d_in[9];
  const float* Wff = (const float*)d_in[10]; const float* bff = (const float*)d_in[11];
  const float* Wg = (const float*)d_in[12];  const float* bg = (const float*)d_in[13];
  const float* Wd = (const float*)d_in[14];  const float* bd = (const float*)d_in[15];
  const float* Wfc = (const float*)d_in[16]; const float* bfc = (const float*)d_in[17];
  float* out = (float*)d_out;

  char* ws = (char*)d_ws;
  size_t off = 0;
  auto alloc = [&](size_t bytes) -> char* {
    char* p = ws + off;
    off = (off + bytes + 255) & ~(size_t)255;
    return p;
  };
  ushort* Wffb = (ushort*)alloc(19660800ull * 2);
  ushort* Wdb  = (ushort*)alloc(3276800ull * 2);
  ushort* Wfcb = (ushort*)alloc(819200ull * 2);
  ushort* Wgb  = (ushort*)alloc(65536ull * 2);
  ushort* cbuf = (ushort*)alloc(2 * CB * 2);   // both branches; later aliased as du
  ushort* h    = (ushort*)alloc(2 * HB * 2);   // both branches; later aliased as hg
  ushort* xw   = (ushort*)alloc(2 * HB * 2);   // both branches
  int* deg   = (int*)alloc(2 * NTOT * 4);
  int* offs  = (int*)alloc(2 * (NTOT + 1) * 4);
  int* curs  = (int*)alloc(2 * NTOT * 4);
  int* csr   = (int*)alloc(2 * NE * 4);
  float* nrm = (float*)alloc(2 * NTOT * 4);
  ushort* du = cbuf;  // alias: cbuf free after merged FF GEMM

  hipMemsetAsync(deg, 0, 2 * NTOT * 4, stream);
  hipMemsetAsync(out, 0, (size_t)out_size * 4, stream);

  cvt_k<<<23264, 256, 0, stream>>>(Wff, Wd, Wfc, Wg, Wffb, Wdb, Wfcb, Wgb);

  // CSR build, both edge sets in single launches
  hist_k<<<3200, 256, 0, stream>>>(e1 + NE, e2 + NE, deg);
  scan_k<<<2, 1024, 0, stream>>>(deg, offs, curs, nrm);
  fill_k<<<3200, 256, 0, stream>>>(e1, e2, curs, csr);

  // both branches per stage
  conv_k<<<NTOT, 256, 0, stream>>>(x1, x2, w3, b3, w5, b5, w7, b7, cbuf);
  gemm_k<0><<<dim3(4, 200), 256, 0, stream>>>(cbuf, nullptr, Wffb, h, nullptr, bff);
  gemm_k<1><<<800, 256, 0, stream>>>(h, nullptr, Wgb, xw, nullptr, nrm);
  agg_k<<<12800, 256, 0, stream>>>(xw, offs, csr, nrm, bg, h);   // hg overwrites h

  // discrepancy FC + final FC
  gemm_k<2><<<dim3(2, 100), 256, 0, stream>>>(h, h + HB, Wdb, du, nullptr, bd);
  gemm_k<3><<<dim3(2, 25), 256, 0, stream>>>(du, nullptr, Wfcb, nullptr, out, bfc);
}

// Round 5
// 327.148 us; speedup vs baseline: 1.3492x; 1.1040x over previous
//
#include <hip/hip_runtime.h>

#define DI __device__ __forceinline__

typedef __bf16 bf16_t;
typedef bf16_t bf16x8 __attribute__((ext_vector_type(8)));
typedef float f32x4 __attribute__((ext_vector_type(4)));
typedef ushort ushort8v __attribute__((ext_vector_type(8)));

static constexpr int NNODE = 100, WIN = 128, GH = 256, DH = 64, OUTC = 128, NB = 256;
static constexpr int NTOT = NB * NNODE;   // 25600
static constexpr int NE = 409600;
static constexpr int FFK = 6 * WIN;       // 768
static constexpr size_t CB = (size_t)NNODE * NB * FFK;   // per-branch conv buf elems (19,660,800)
static constexpr size_t HB = (size_t)NTOT * GH;          // per-branch h/xw elems (6,553,600)

DI ushort f2bf(float f) {
  union { float f; unsigned u; } v; v.f = f;
  unsigned r = v.u + 0x7fffu + ((v.u >> 16) & 1u);
  return (ushort)(r >> 16);
}
DI float bf2f(ushort s) {
  union { unsigned u; float f; } v; v.u = ((unsigned)s) << 16; return v.f;
}

DI void gload16(const void* g, void* l) {
  __builtin_amdgcn_global_load_lds((const __attribute__((address_space(1))) void*)g,
                                   (__attribute__((address_space(3))) void*)l, 16, 0, 0);
}

// ---------- weight conversion f32 -> bf16 (Wff, Wd, Wfc, Wg) ----------
__global__ void cvt_k(const float* __restrict__ s0, const float* __restrict__ s1,
                      const float* __restrict__ s2, const float* __restrict__ s3,
                      ushort* __restrict__ d0, ushort* __restrict__ d1,
                      ushort* __restrict__ d2, ushort* __restrict__ d3) {
  int j = blockIdx.x * 256 + threadIdx.x;   // vec4 index
  const float* s; ushort* d;
  if (j < 19660800 / 4) { s = s0; d = d0; }
  else if ((j -= 19660800 / 4) < 3276800 / 4) { s = s1; d = d1; }
  else if ((j -= 3276800 / 4) < 819200 / 4) { s = s2; d = d2; }
  else { j -= 819200 / 4; s = s3; d = d3; }
  float4 v = reinterpret_cast<const float4*>(s)[j];
  ushort4 o;
  o.x = f2bf(v.x); o.y = f2bf(v.y); o.z = f2bf(v.z); o.w = f2bf(v.w);
  reinterpret_cast<ushort4*>(d)[j] = o;
}

// ---------- multiscale conv, BOTH branches; 16 rows/block, 8 outputs/thread ----------
// c layout: [br][node][b][768], f = cidx*128 + w
__global__ __launch_bounds__(256) void conv_k(
    const float* __restrict__ x1, const float* __restrict__ x2,
    const float* __restrict__ w3, const float* __restrict__ b3,
    const float* __restrict__ w5, const float* __restrict__ b5,
    const float* __restrict__ w7, const float* __restrict__ b7,
    ushort* __restrict__ c) {
  const int t = threadIdx.x;
  const int rowi = t >> 4;          // 0..15
  const int idx = t & 15;           // 0..15, w0 = idx*8
  int r = blockIdx.x * 16 + rowi;   // [0, 51200)
  int br = r >= NTOT;
  int rr = r - br * NTOT;
  const float* x = br ? x2 : x1;
  int b = rr / 100, node = rr - b * 100;

  __shared__ float xs[16][136];
  const int w0 = idx * 8;
  // stage row: two float4 loads per thread
  float4 v0 = *reinterpret_cast<const float4*>(x + (size_t)rr * WIN + w0);
  float4 v1 = *reinterpret_cast<const float4*>(x + (size_t)rr * WIN + w0 + 4);
  *reinterpret_cast<float4*>(&xs[rowi][4 + w0]) = v0;
  *reinterpret_cast<float4*>(&xs[rowi][4 + w0 + 4]) = v1;
  if (idx == 0) { xs[rowi][0] = 0.f; xs[rowi][1] = 0.f; xs[rowi][2] = 0.f; xs[rowi][3] = 0.f; }
  if (idx == 15) { xs[rowi][132] = 0.f; xs[rowi][133] = 0.f; xs[rowi][134] = 0.f; xs[rowi][135] = 0.f; }
  __syncthreads();

  float xv[14];
#pragma unroll
  for (int j = 0; j < 14; ++j) xv[j] = xs[rowi][1 + w0 + j];   // covers w0-3 .. w0+10

  const float* W3 = w3 + node * 6;  const float* B3 = b3 + node * 2;
  const float* W5 = w5 + node * 10; const float* B5 = b5 + node * 2;
  const float* W7 = w7 + node * 14; const float* B7 = b7 + node * 2;
  ushort* out = c + (size_t)br * CB + (size_t)(node * NB + b) * FFK + w0;

#pragma unroll
  for (int ch = 0; ch < 2; ++ch) {
    float k3[3], k5[5], k7[7];
#pragma unroll
    for (int j = 0; j < 3; ++j) k3[j] = W3[ch * 3 + j];
#pragma unroll
    for (int j = 0; j < 5; ++j) k5[j] = W5[ch * 5 + j];
#pragma unroll
    for (int j = 0; j < 7; ++j) k7[j] = W7[ch * 7 + j];
    float bb3 = B3[ch], bb5 = B5[ch], bb7 = B7[ch];
    ushort8v o3, o5, o7;
#pragma unroll
    for (int p = 0; p < 8; ++p) {
      float a3 = bb3, a5 = bb5, a7 = bb7;
#pragma unroll
      for (int j = 0; j < 3; ++j) a3 += k3[j] * xv[p + 2 + j];
#pragma unroll
      for (int j = 0; j < 5; ++j) a5 += k5[j] * xv[p + 1 + j];
#pragma unroll
      for (int j = 0; j < 7; ++j) a7 += k7[j] * xv[p + j];
      o3[p] = f2bf(fmaxf(a3, 0.f));
      o5[p] = f2bf(fmaxf(a5, 0.f));
      o7[p] = f2bf(fmaxf(a7, 0.f));
    }
    *reinterpret_cast<ushort8v*>(out + (0 + ch) * WIN) = o3;
    *reinterpret_cast<ushort8v*>(out + (2 + ch) * WIN) = o5;
    *reinterpret_cast<ushort8v*>(out + (4 + ch) * WIN) = o7;
  }
}

// ---------- degree histogram, both edge sets ----------
__global__ void hist_k(const int* __restrict__ d1, const int* __restrict__ d2,
                       int* __restrict__ deg) {
  int i = blockIdx.x * 256 + threadIdx.x;
  if (i < NE) atomicAdd(&deg[d1[i]], 1);
  else if (i < 2 * NE) atomicAdd(&deg[NTOT + d2[i - NE]], 1);
}

// ---------- 2-block scan: offs/cursor/norm, one block per edge set ----------
__global__ __launch_bounds__(1024) void scan_k(const int* __restrict__ deg_, int* __restrict__ offs_,
                                               int* __restrict__ cursor_, float* __restrict__ norm_) {
  int set = blockIdx.x;
  const int* deg = deg_ + set * NTOT;
  int* offs = offs_ + set * (NTOT + 1);
  int* cursor = cursor_ + set * NTOT;
  float* norm = norm_ + set * NTOT;
  __shared__ int part[1024];
  int t = threadIdx.x;
  int base = t * 25;
  int local[25];
  int s = 0;
#pragma unroll
  for (int j = 0; j < 25; ++j) { local[j] = s; s += deg[base + j]; }
  part[t] = s;
  __syncthreads();
  for (int d = 1; d < 1024; d <<= 1) {
    int vv = (t >= d) ? part[t - d] : 0;
    __syncthreads();
    part[t] += vv;
    __syncthreads();
  }
  int excl = (t > 0) ? part[t - 1] : 0;
#pragma unroll
  for (int j = 0; j < 25; ++j) {
    int o = excl + local[j];
    offs[base + j] = o;
    cursor[base + j] = o;
    norm[base + j] = rsqrtf((float)(deg[base + j] + 1));   // +1 self loop
  }
  if (t == 1023) offs[NTOT] = part[1023];
}

// ---------- CSR fill, both edge sets ----------
__global__ void fill_k(const int* __restrict__ e1, const int* __restrict__ e2,
                       int* __restrict__ cursor, int* __restrict__ csr) {
  int i = blockIdx.x * 256 + threadIdx.x;
  if (i < NE) {
    int d = e1[NE + i];
    int pos = atomicAdd(&cursor[d], 1);
    csr[pos] = e1[i];
  } else if (i < 2 * NE) {
    int d = e2[NE + i - NE];
    int pos = atomicAdd(&cursor[NTOT + d], 1);
    csr[NE + pos] = e2[i - NE];
  }
}

// ---------- GCN aggregation, both branches: one wave per dst node ----------
// xw rows PRE-SCALED by norm[src]; hg[v] = relu(norm[v]*(xw'[v]+sum xw'[csr[j]]) + bg)
__global__ __launch_bounds__(256) void agg_k(const ushort* __restrict__ xw_, const int* __restrict__ offs_,
                                             const int* __restrict__ csr_, const float* __restrict__ norm_,
                                             const float* __restrict__ bg, ushort* __restrict__ hg_) {
  int idx = blockIdx.x * 4 + (threadIdx.x >> 6);   // [0, 51200)
  int br = idx >= NTOT;
  int v = idx - br * NTOT;
  const ushort* xw = xw_ + (size_t)br * HB;
  const int* offs = offs_ + br * (NTOT + 1);
  const int* csr = csr_ + br * NE;
  const float* norm = norm_ + br * NTOT;
  ushort* hg = hg_ + (size_t)br * HB;

  int lane = threadIdx.x & 63;
  int half = lane >> 5;
  int colb = (lane & 31) * 8;           // 8 bf16 per lane, 32 lanes cover the 256-wide row
  const ushort* base = xw + colb;

  float a[8] = {0.f, 0.f, 0.f, 0.f, 0.f, 0.f, 0.f, 0.f};
  if (half == 0) {                       // self loop (once)
    ushort8v q = *reinterpret_cast<const ushort8v*>(base + (size_t)v * GH);
#pragma unroll
    for (int i = 0; i < 8; ++i) a[i] += bf2f(q[i]);
  }
  int e0 = offs[v], e1 = offs[v + 1];
  int j = e0 + half;                     // this half owns edges at stride 2
  for (; j + 6 < e1; j += 8) {
    int s0 = csr[j], s1 = csr[j + 2], s2 = csr[j + 4], s3 = csr[j + 6];
    ushort8v q0 = *reinterpret_cast<const ushort8v*>(base + (size_t)s0 * GH);
    ushort8v q1 = *reinterpret_cast<const ushort8v*>(base + (size_t)s1 * GH);
    ushort8v q2 = *reinterpret_cast<const ushort8v*>(base + (size_t)s2 * GH);
    ushort8v q3 = *reinterpret_cast<const ushort8v*>(base + (size_t)s3 * GH);
#pragma unroll
    for (int i = 0; i < 8; ++i)
      a[i] += (bf2f(q0[i]) + bf2f(q1[i])) + (bf2f(q2[i]) + bf2f(q3[i]));
  }
  for (; j + 2 < e1; j += 4) {
    int s0 = csr[j], s1 = csr[j + 2];
    ushort8v q0 = *reinterpret_cast<const ushort8v*>(base + (size_t)s0 * GH);
    ushort8v q1 = *reinterpret_cast<const ushort8v*>(base + (size_t)s1 * GH);
#pragma unroll
    for (int i = 0; i < 8; ++i) a[i] += bf2f(q0[i]) + bf2f(q1[i]);
  }
  if (j < e1) {
    int s0 = csr[j];
    ushort8v q0 = *reinterpret_cast<const ushort8v*>(base + (size_t)s0 * GH);
#pragma unroll
    for (int i = 0; i < 8; ++i) a[i] += bf2f(q0[i]);
  }
#pragma unroll
  for (int i = 0; i < 8; ++i) a[i] += __shfl_xor(a[i], 32);

  if (half == 0) {
    float nv = norm[v];
    float4 bb0 = *reinterpret_cast<const float4*>(bg + colb);
    float4 bb1 = *reinterpret_cast<const float4*>(bg + colb + 4);
    ushort8v o;
    o[0] = f2bf(fmaxf(nv * a[0] + bb0.x, 0.f));
    o[1] = f2bf(fmaxf(nv * a[1] + bb0.y, 0.f));
    o[2] = f2bf(fmaxf(nv * a[2] + bb0.z, 0.f));
    o[3] = f2bf(fmaxf(nv * a[3] + bb0.w, 0.f));
    o[4] = f2bf(fmaxf(nv * a[4] + bb1.x, 0.f));
    o[5] = f2bf(fmaxf(nv * a[5] + bb1.y, 0.f));
    o[6] = f2bf(fmaxf(nv * a[6] + bb1.z, 0.f));
    o[7] = f2bf(fmaxf(nv * a[7] + bb1.w, 0.f));
    *reinterpret_cast<ushort8v*>(hg + (size_t)v * GH + colb) = o;
  }
}

// ---------- BT GEMM, 128xBN tile, BK=64, global_load_lds staging ----------
// MODE 0 (both branches): h = relu(c @ Wff[node]^T + bff[node])   grid (4, 200)
// MODE 1 (both branches): xw' = nrm * (h @ Wg^T)                  grid 800
// MODE 2: du = relu(cat(hg1,hg2) @ Wd[node]^T + bd)               grid (2, 100)
// MODE 3: out += du @ Wfc^T (+bfc on y==0), K-split atomics       grid (2, 25)
template <int MODE>
__global__ __launch_bounds__(256) void gemm_k(const ushort* __restrict__ A, const ushort* __restrict__ A2,
                                              const ushort* __restrict__ Bm, ushort* __restrict__ obf,
                                              float* __restrict__ of, const float* __restrict__ bias) {
  constexpr int BN = (MODE == 2) ? 64 : 128;
  constexpr int KT = (MODE == 0) ? 12 : (MODE == 1) ? 4 : (MODE == 2) ? 8 : 4;
  constexpr int LDA = (MODE == 0) ? 768 : (MODE == 1) ? 256 : (MODE == 2) ? 256 : 6400;
  constexpr int LDB = (MODE == 0) ? 768 : (MODE == 1) ? 256 : (MODE == 2) ? 512 : 6400;
  constexpr int MF = (MODE == 2) ? 2 : 4;
  constexpr int NF = 4;

  __shared__ ushort As[128 * 64];
  __shared__ ushort Bs[BN * 64];

  const int tid = threadIdx.x, wv = tid >> 6, lane = tid & 63;

  int mt = 0, nt = 0, node = 0, kbase = 0, br = 0;
  if constexpr (MODE == 0) { mt = blockIdx.x >> 1; nt = blockIdx.x & 1;
                             br = blockIdx.y >= 100; node = blockIdx.y - br * 100; }
  else if constexpr (MODE == 1) { int bx = blockIdx.x; br = bx >= 400; bx -= br * 400;
                                  mt = bx >> 1; nt = bx & 1; }
  else if constexpr (MODE == 2) { mt = blockIdx.x; node = blockIdx.y; }
  else { mt = blockIdx.x; kbase = blockIdx.y * 256; }

  const ushort* Ab = nullptr; const ushort* Bb = nullptr;
  if constexpr (MODE == 0) { Ab = A + (size_t)br * CB + (size_t)node * (NB * FFK) + (size_t)mt * 128 * FFK;
                             Bb = Bm + (size_t)node * (GH * FFK) + (size_t)nt * 128 * FFK; }
  else if constexpr (MODE == 1) { Ab = A + (size_t)br * HB + (size_t)mt * 128 * GH;
                                  Bb = Bm + (size_t)nt * 128 * GH; }
  else if constexpr (MODE == 2) { Bb = Bm + (size_t)node * (DH * 512); }
  else { Ab = A + (size_t)mt * 128 * 6400 + kbase; Bb = Bm + kbase; }

  const int wr = (MODE == 2) ? wv : (wv >> 1);
  const int wc = (MODE == 2) ? 0 : (wv & 1);

  f32x4 acc[MF][NF] = {};

  for (int kt = 0; kt < KT; ++kt) {
    const int k0 = kt * 64;
    __syncthreads();
#pragma unroll
    for (int it = 0; it < 4; ++it) {
      int rb = it * 32 + wv * 8;
      int row = rb + (lane >> 3);
      const ushort* gp;
      if constexpr (MODE == 2) {
        int b_ = mt * 128 + row;
        const ushort* src = (k0 < 256) ? A : A2;
        gp = src + (size_t)(b_ * NNODE + node) * GH + (k0 & 255) + (lane & 7) * 8;
      } else {
        gp = Ab + (size_t)row * LDA + k0 + (lane & 7) * 8;
      }
      gload16(gp, &As[rb * 64]);
    }
#pragma unroll
    for (int it = 0; it < BN / 32; ++it) {
      int rb = it * 32 + wv * 8;
      int row = rb + (lane >> 3);
      gload16(Bb + (size_t)row * LDB + k0 + (lane & 7) * 8, &Bs[rb * 64]);
    }
    __syncthreads();
#pragma unroll
    for (int kk = 0; kk < 2; ++kk) {
      bf16x8 af[MF], bfr[NF];
#pragma unroll
      for (int m = 0; m < MF; ++m) {
        int rr = wr * (MF * 16) + m * 16 + (lane & 15);
        af[m] = *reinterpret_cast<const bf16x8*>(&As[rr * 64 + kk * 32 + (lane >> 4) * 8]);
      }
#pragma unroll
      for (int n = 0; n < NF; ++n) {
        int rr = wc * 64 + n * 16 + (lane & 15);
        bfr[n] = *reinterpret_cast<const bf16x8*>(&Bs[rr * 64 + kk * 32 + (lane >> 4) * 8]);
      }
#pragma unroll
      for (int m = 0; m < MF; ++m)
#pragma unroll
        for (int n = 0; n < NF; ++n)
          acc[m][n] = __builtin_amdgcn_mfma_f32_16x16x32_bf16(af[m], bfr[n], acc[m][n], 0, 0, 0);
    }
  }

  const int lrow = (lane >> 4) * 4, lcol = lane & 15;
#pragma unroll
  for (int m = 0; m < MF; ++m) {
#pragma unroll
    for (int n = 0; n < NF; ++n) {
      int cc = wc * 64 + n * 16 + lcol;
#pragma unroll
      for (int rg = 0; rg < 4; ++rg) {
        int rr = wr * (MF * 16) + m * 16 + lrow + rg;
        float val = acc[m][n][rg];
        if constexpr (MODE == 0) {
          int b_ = mt * 128 + rr;
          int col = nt * 128 + cc;
          val = fmaxf(val + bias[node * GH + col], 0.f);
          obf[(size_t)br * HB + (size_t)(b_ * NNODE + node) * GH + col] = f2bf(val);
        } else if constexpr (MODE == 1) {
          int R = mt * 128 + rr;
          int col = nt * 128 + cc;
          obf[(size_t)br * HB + (size_t)R * GH + col] = f2bf(val * bias[br * NTOT + R]);
        } else if constexpr (MODE == 2) {
          int b_ = mt * 128 + rr;
          val = fmaxf(val + bias[node * DH + cc], 0.f);
          obf[(size_t)b_ * (NNODE * DH) + node * DH + cc] = f2bf(val);
        } else {
          int R = mt * 128 + rr;
          if (blockIdx.y == 0) val += bias[cc];
          atomicAdd(&of[R * OUTC + cc], val);
        }
      }
    }
  }
}

extern "C" void kernel_launch(void* const* d_in, const int* in_sizes, int n_in,
                              void* d_out, int out_size, void* d_ws, size_t ws_size,
                              hipStream_t stream) {
  const float* x1 = (const float*)d_in[0];
  const float* x2 = (const float*)d_in[1];
  const int* e1 = (const int*)d_in[2];
  const int* e2 = (const int*)d_in[3];
  const float* w3 = (const float*)d_in[4];  const float* b3 = (const float*)d_in[5];
  const float* w5 = (const float*)d_in[6];  const float* b5 = (const float*)d_in[7];
  const float* w7 = (const float*)d_in[8];  const float* b7 = (const float*)d_in[9];
  const float* Wff = (const float*)d_in[10]; const float* bff = (const float*)d_in[11];
  const float* Wg = (const float*)d_in[12];  const float* bg = (const float*)d_in[13];
  const float* Wd = (const float*)d_in[14];  const float* bd = (const float*)d_in[15];
  const float* Wfc = (const float*)d_in[16]; const float* bfc = (const float*)d_in[17];
  float* out = (float*)d_out;

  char* ws = (char*)d_ws;
  size_t off = 0;
  auto alloc = [&](size_t bytes) -> char* {
    char* p = ws + off;
    off = (off + bytes + 255) & ~(size_t)255;
    return p;
  };
  ushort* Wffb = (ushort*)alloc(19660800ull * 2);
  ushort* Wdb  = (ushort*)alloc(3276800ull * 2);
  ushort* Wfcb = (ushort*)alloc(819200ull * 2);
  ushort* Wgb  = (ushort*)alloc(65536ull * 2);
  ushort* cbuf = (ushort*)alloc(2 * CB * 2);   // both branches; later aliased as du
  ushort* h    = (ushort*)alloc(2 * HB * 2);   // both branches; later aliased as hg
  ushort* xw   = (ushort*)alloc(2 * HB * 2);   // both branches
  int* deg   = (int*)alloc(2 * NTOT * 4);
  int* offs  = (int*)alloc(2 * (NTOT + 1) * 4);
  int* curs  = (int*)alloc(2 * NTOT * 4);
  int* csr   = (int*)alloc(2 * NE * 4);
  float* nrm = (float*)alloc(2 * NTOT * 4);
  ushort* du = cbuf;  // alias: cbuf free after merged FF GEMM

  hipMemsetAsync(deg, 0, 2 * NTOT * 4, stream);
  hipMemsetAsync(out, 0, (size_t)out_size * 4, stream);

  cvt_k<<<23264, 256, 0, stream>>>(Wff, Wd, Wfc, Wg, Wffb, Wdb, Wfcb, Wgb);

  // CSR build, both edge sets in single launches
  hist_k<<<3200, 256, 0, stream>>>(e1 + NE, e2 + NE, deg);
  scan_k<<<2, 1024, 0, stream>>>(deg, offs, curs, nrm);
  fill_k<<<3200, 256, 0, stream>>>(e1, e2, curs, csr);

  // both branches per stage
  conv_k<<<3200, 256, 0, stream>>>(x1, x2, w3, b3, w5, b5, w7, b7, cbuf);
  gemm_k<0><<<dim3(4, 200), 256, 0, stream>>>(cbuf, nullptr, Wffb, h, nullptr, bff);
  gemm_k<1><<<800, 256, 0, stream>>>(h, nullptr, Wgb, xw, nullptr, nrm);
  agg_k<<<12800, 256, 0, stream>>>(xw, offs, csr, nrm, bg, h);   // hg overwrites h

  // discrepancy FC + final FC
  gemm_k<2><<<dim3(2, 100), 256, 0, stream>>>(h, h + HB, Wdb, du, nullptr, bd);
  gemm_k<3><<<dim3(2, 25), 256, 0, stream>>>(du, nullptr, Wfcb, nullptr, out, bfc);
}

// Round 6
// 312.660 us; speedup vs baseline: 1.4117x; 1.0463x over previous
//
#include <hip/hip_runtime.h>

#define DI __device__ __forceinline__

typedef __bf16 bf16_t;
typedef bf16_t bf16x8 __attribute__((ext_vector_type(8)));
typedef float f32x4 __attribute__((ext_vector_type(4)));
typedef ushort ushort8v __attribute__((ext_vector_type(8)));

static constexpr int NNODE = 100, WIN = 128, GH = 256, DH = 64, OUTC = 128, NB = 256;
static constexpr int NTOT = NB * NNODE;   // 25600
static constexpr int NE = 409600;
static constexpr int FFK = 6 * WIN;       // 768
static constexpr size_t CB = (size_t)NNODE * NB * FFK;   // per-branch conv buf elems (19,660,800)
static constexpr size_t HB = (size_t)NTOT * GH;          // per-branch h/xw elems (6,553,600)

DI ushort f2bf(float f) {
  union { float f; unsigned u; } v; v.f = f;
  unsigned r = v.u + 0x7fffu + ((v.u >> 16) & 1u);
  return (ushort)(r >> 16);
}
DI float bf2f(ushort s) {
  union { unsigned u; float f; } v; v.u = ((unsigned)s) << 16; return v.f;
}

DI void gload16(const void* g, void* l) {
  __builtin_amdgcn_global_load_lds((const __attribute__((address_space(1))) void*)g,
                                   (__attribute__((address_space(3))) void*)l, 16, 0, 0);
}

// ---------- weight conversion f32 -> bf16 (Wff, Wd, Wfc, Wg) ----------
__global__ void cvt_k(const float* __restrict__ s0, const float* __restrict__ s1,
                      const float* __restrict__ s2, const float* __restrict__ s3,
                      ushort* __restrict__ d0, ushort* __restrict__ d1,
                      ushort* __restrict__ d2, ushort* __restrict__ d3) {
  int j = blockIdx.x * 256 + threadIdx.x;   // vec4 index
  const float* s; ushort* d;
  if (j < 19660800 / 4) { s = s0; d = d0; }
  else if ((j -= 19660800 / 4) < 3276800 / 4) { s = s1; d = d1; }
  else if ((j -= 3276800 / 4) < 819200 / 4) { s = s2; d = d2; }
  else { j -= 819200 / 4; s = s3; d = d3; }
  float4 v = reinterpret_cast<const float4*>(s)[j];
  ushort4 o;
  o.x = f2bf(v.x); o.y = f2bf(v.y); o.z = f2bf(v.z); o.w = f2bf(v.w);
  reinterpret_cast<ushort4*>(d)[j] = o;
}

// ---------- multiscale conv, BOTH branches; 16 rows/block, 8 outputs/thread ----------
__global__ __launch_bounds__(256) void conv_k(
    const float* __restrict__ x1, const float* __restrict__ x2,
    const float* __restrict__ w3, const float* __restrict__ b3,
    const float* __restrict__ w5, const float* __restrict__ b5,
    const float* __restrict__ w7, const float* __restrict__ b7,
    ushort* __restrict__ c) {
  const int t = threadIdx.x;
  const int rowi = t >> 4;          // 0..15
  const int idx = t & 15;           // 0..15, w0 = idx*8
  int r = blockIdx.x * 16 + rowi;   // [0, 51200)
  int br = r >= NTOT;
  int rr = r - br * NTOT;
  const float* x = br ? x2 : x1;
  int b = rr / 100, node = rr - b * 100;

  __shared__ float xs[16][136];
  const int w0 = idx * 8;
  float4 v0 = *reinterpret_cast<const float4*>(x + (size_t)rr * WIN + w0);
  float4 v1 = *reinterpret_cast<const float4*>(x + (size_t)rr * WIN + w0 + 4);
  *reinterpret_cast<float4*>(&xs[rowi][4 + w0]) = v0;
  *reinterpret_cast<float4*>(&xs[rowi][4 + w0 + 4]) = v1;
  if (idx == 0) { xs[rowi][0] = 0.f; xs[rowi][1] = 0.f; xs[rowi][2] = 0.f; xs[rowi][3] = 0.f; }
  if (idx == 15) { xs[rowi][132] = 0.f; xs[rowi][133] = 0.f; xs[rowi][134] = 0.f; xs[rowi][135] = 0.f; }
  __syncthreads();

  float xv[14];
#pragma unroll
  for (int j = 0; j < 14; ++j) xv[j] = xs[rowi][1 + w0 + j];

  const float* W3 = w3 + node * 6;  const float* B3 = b3 + node * 2;
  const float* W5 = w5 + node * 10; const float* B5 = b5 + node * 2;
  const float* W7 = w7 + node * 14; const float* B7 = b7 + node * 2;
  ushort* out = c + (size_t)br * CB + (size_t)(node * NB + b) * FFK + w0;

#pragma unroll
  for (int ch = 0; ch < 2; ++ch) {
    float k3[3], k5[5], k7[7];
#pragma unroll
    for (int j = 0; j < 3; ++j) k3[j] = W3[ch * 3 + j];
#pragma unroll
    for (int j = 0; j < 5; ++j) k5[j] = W5[ch * 5 + j];
#pragma unroll
    for (int j = 0; j < 7; ++j) k7[j] = W7[ch * 7 + j];
    float bb3 = B3[ch], bb5 = B5[ch], bb7 = B7[ch];
    ushort8v o3, o5, o7;
#pragma unroll
    for (int p = 0; p < 8; ++p) {
      float a3 = bb3, a5 = bb5, a7 = bb7;
#pragma unroll
      for (int j = 0; j < 3; ++j) a3 += k3[j] * xv[p + 2 + j];
#pragma unroll
      for (int j = 0; j < 5; ++j) a5 += k5[j] * xv[p + 1 + j];
#pragma unroll
      for (int j = 0; j < 7; ++j) a7 += k7[j] * xv[p + j];
      o3[p] = f2bf(fmaxf(a3, 0.f));
      o5[p] = f2bf(fmaxf(a5, 0.f));
      o7[p] = f2bf(fmaxf(a7, 0.f));
    }
    *reinterpret_cast<ushort8v*>(out + (0 + ch) * WIN) = o3;
    *reinterpret_cast<ushort8v*>(out + (2 + ch) * WIN) = o5;
    *reinterpret_cast<ushort8v*>(out + (4 + ch) * WIN) = o7;
  }
}

// ---------- degree histogram, both edge sets ----------
__global__ void hist_k(const int* __restrict__ d1, const int* __restrict__ d2,
                       int* __restrict__ deg) {
  int i = blockIdx.x * 256 + threadIdx.x;
  if (i < NE) atomicAdd(&deg[d1[i]], 1);
  else if (i < 2 * NE) atomicAdd(&deg[NTOT + d2[i - NE]], 1);
}

// ---------- 2-block scan: offs/cursor/norm, one block per edge set ----------
__global__ __launch_bounds__(1024) void scan_k(const int* __restrict__ deg_, int* __restrict__ offs_,
                                               int* __restrict__ cursor_, float* __restrict__ norm_) {
  int set = blockIdx.x;
  const int* deg = deg_ + set * NTOT;
  int* offs = offs_ + set * (NTOT + 1);
  int* cursor = cursor_ + set * NTOT;
  float* norm = norm_ + set * NTOT;
  __shared__ int part[1024];
  int t = threadIdx.x;
  int base = t * 25;
  int local[25];
  int s = 0;
#pragma unroll
  for (int j = 0; j < 25; ++j) { local[j] = s; s += deg[base + j]; }
  part[t] = s;
  __syncthreads();
  for (int d = 1; d < 1024; d <<= 1) {
    int vv = (t >= d) ? part[t - d] : 0;
    __syncthreads();
    part[t] += vv;
    __syncthreads();
  }
  int excl = (t > 0) ? part[t - 1] : 0;
#pragma unroll
  for (int j = 0; j < 25; ++j) {
    int o = excl + local[j];
    offs[base + j] = o;
    cursor[base + j] = o;
    norm[base + j] = rsqrtf((float)(deg[base + j] + 1));   // +1 self loop
  }
  if (t == 1023) offs[NTOT] = part[1023];
}

// ---------- CSR fill, both edge sets ----------
__global__ void fill_k(const int* __restrict__ e1, const int* __restrict__ e2,
                       int* __restrict__ cursor, int* __restrict__ csr) {
  int i = blockIdx.x * 256 + threadIdx.x;
  if (i < NE) {
    int d = e1[NE + i];
    int pos = atomicAdd(&cursor[d], 1);
    csr[pos] = e1[i];
  } else if (i < 2 * NE) {
    int d = e2[NE + i - NE];
    int pos = atomicAdd(&cursor[NTOT + d], 1);
    csr[NE + pos] = e2[i - NE];
  }
}

// ---------- GCN aggregation, both branches: one wave per dst node ----------
__global__ __launch_bounds__(256) void agg_k(const ushort* __restrict__ xw_, const int* __restrict__ offs_,
                                             const int* __restrict__ csr_, const float* __restrict__ norm_,
                                             const float* __restrict__ bg, ushort* __restrict__ hg_) {
  int idx = blockIdx.x * 4 + (threadIdx.x >> 6);   // [0, 51200)
  int br = idx >= NTOT;
  int v = idx - br * NTOT;
  const ushort* xw = xw_ + (size_t)br * HB;
  const int* offs = offs_ + br * (NTOT + 1);
  const int* csr = csr_ + br * NE;
  const float* norm = norm_ + br * NTOT;
  ushort* hg = hg_ + (size_t)br * HB;

  int lane = threadIdx.x & 63;
  int half = lane >> 5;
  int colb = (lane & 31) * 8;
  const ushort* base = xw + colb;

  float a[8] = {0.f, 0.f, 0.f, 0.f, 0.f, 0.f, 0.f, 0.f};
  if (half == 0) {
    ushort8v q = *reinterpret_cast<const ushort8v*>(base + (size_t)v * GH);
#pragma unroll
    for (int i = 0; i < 8; ++i) a[i] += bf2f(q[i]);
  }
  int e0 = offs[v], e1 = offs[v + 1];
  int j = e0 + half;
  for (; j + 6 < e1; j += 8) {
    int s0 = csr[j], s1 = csr[j + 2], s2 = csr[j + 4], s3 = csr[j + 6];
    ushort8v q0 = *reinterpret_cast<const ushort8v*>(base + (size_t)s0 * GH);
    ushort8v q1 = *reinterpret_cast<const ushort8v*>(base + (size_t)s1 * GH);
    ushort8v q2 = *reinterpret_cast<const ushort8v*>(base + (size_t)s2 * GH);
    ushort8v q3 = *reinterpret_cast<const ushort8v*>(base + (size_t)s3 * GH);
#pragma unroll
    for (int i = 0; i < 8; ++i)
      a[i] += (bf2f(q0[i]) + bf2f(q1[i])) + (bf2f(q2[i]) + bf2f(q3[i]));
  }
  for (; j + 2 < e1; j += 4) {
    int s0 = csr[j], s1 = csr[j + 2];
    ushort8v q0 = *reinterpret_cast<const ushort8v*>(base + (size_t)s0 * GH);
    ushort8v q1 = *reinterpret_cast<const ushort8v*>(base + (size_t)s1 * GH);
#pragma unroll
    for (int i = 0; i < 8; ++i) a[i] += bf2f(q0[i]) + bf2f(q1[i]);
  }
  if (j < e1) {
    int s0 = csr[j];
    ushort8v q0 = *reinterpret_cast<const ushort8v*>(base + (size_t)s0 * GH);
#pragma unroll
    for (int i = 0; i < 8; ++i) a[i] += bf2f(q0[i]);
  }
#pragma unroll
  for (int i = 0; i < 8; ++i) a[i] += __shfl_xor(a[i], 32);

  if (half == 0) {
    float nv = norm[v];
    float4 bb0 = *reinterpret_cast<const float4*>(bg + colb);
    float4 bb1 = *reinterpret_cast<const float4*>(bg + colb + 4);
    ushort8v o;
    o[0] = f2bf(fmaxf(nv * a[0] + bb0.x, 0.f));
    o[1] = f2bf(fmaxf(nv * a[1] + bb0.y, 0.f));
    o[2] = f2bf(fmaxf(nv * a[2] + bb0.z, 0.f));
    o[3] = f2bf(fmaxf(nv * a[3] + bb0.w, 0.f));
    o[4] = f2bf(fmaxf(nv * a[4] + bb1.x, 0.f));
    o[5] = f2bf(fmaxf(nv * a[5] + bb1.y, 0.f));
    o[6] = f2bf(fmaxf(nv * a[6] + bb1.z, 0.f));
    o[7] = f2bf(fmaxf(nv * a[7] + bb1.w, 0.f));
    *reinterpret_cast<ushort8v*>(hg + (size_t)v * GH + colb) = o;
  }
}

// ---------- BT GEMM, 128xBN tile, BK=64, global_load_lds staging, XOR-swizzled LDS ----------
// Swizzle (both-sides, rule #21): LDS dest stays LINEAR (gload_lds requirement);
// global source chunk pre-swizzled with j=(lane&7)^(lane>>3)  [staged row&7 == lane>>3],
// LDS read chunk ch=(kk*4+(lane>>4))^(lane&7)                 [fragment row&7 == lane&15&7].
// MODE 0 (both branches): h = relu(c @ Wff[node]^T + bff[node])   grid 800 (XCD-paired)
// MODE 1 (both branches): xw' = nrm * (h @ Wg^T)                  grid 800 (XCD-paired)
// MODE 2: du = relu(cat(hg1,hg2) @ Wd[node]^T + bd)               grid (2, 100)
// MODE 3: out += du @ Wfc^T (+bfc on y==0), K-split atomics       grid (2, 25)
template <int MODE>
__global__ __launch_bounds__(256) void gemm_k(const ushort* __restrict__ A, const ushort* __restrict__ A2,
                                              const ushort* __restrict__ Bm, ushort* __restrict__ obf,
                                              float* __restrict__ of, const float* __restrict__ bias) {
  constexpr int BN = (MODE == 2) ? 64 : 128;
  constexpr int KT = (MODE == 0) ? 12 : (MODE == 1) ? 4 : (MODE == 2) ? 8 : 4;
  constexpr int LDA = (MODE == 0) ? 768 : (MODE == 1) ? 256 : (MODE == 2) ? 256 : 6400;
  constexpr int LDB = (MODE == 0) ? 768 : (MODE == 1) ? 256 : (MODE == 2) ? 512 : 6400;
  constexpr int MF = (MODE == 2) ? 2 : 4;
  constexpr int NF = 4;

  __shared__ ushort As[128 * 64];
  __shared__ ushort Bs[BN * 64];

  const int tid = threadIdx.x, wv = tid >> 6, lane = tid & 63;
  const int j8 = (((lane & 7) ^ (lane >> 3)) - (lane & 7)) * 8;  // delta vs linear chunk

  int mt = 0, nt = 0, node = 0, kbase = 0, br = 0;
  if constexpr (MODE == 0) {
    // XCD-pair swizzle: chunks of 100 consecutive s per XCD; s groups the 4 blocks of a node
    int h = blockIdx.x;                    // 0..799
    int s = (h & 7) * 100 + (h >> 3);      // bijective (800 % 8 == 0)
    nt = s & 1; int rest = s >> 1;         // 0..399
    mt = rest & 1; int yy = rest >> 1;     // 0..199
    br = yy >= 100; node = yy - br * 100;
  } else if constexpr (MODE == 1) {
    int h = blockIdx.x;
    int s = (h & 7) * 100 + (h >> 3);
    nt = s & 1; int rest = s >> 1;         // 0..399
    br = rest >= 200; mt = rest - br * 200;
  } else if constexpr (MODE == 2) { mt = blockIdx.x; node = blockIdx.y; }
  else { mt = blockIdx.x; kbase = blockIdx.y * 256; }

  const ushort* Ab = nullptr; const ushort* Bb = nullptr;
  if constexpr (MODE == 0) { Ab = A + (size_t)br * CB + (size_t)node * (NB * FFK) + (size_t)mt * 128 * FFK;
                             Bb = Bm + (size_t)node * (GH * FFK) + (size_t)nt * 128 * FFK; }
  else if constexpr (MODE == 1) { Ab = A + (size_t)br * HB + (size_t)mt * 128 * GH;
                                  Bb = Bm + (size_t)nt * 128 * GH; }
  else if constexpr (MODE == 2) { Bb = Bm + (size_t)node * (DH * 512); }
  else { Ab = A + (size_t)mt * 128 * 6400 + kbase; Bb = Bm + kbase; }

  const int wr = (MODE == 2) ? wv : (wv >> 1);
  const int wc = (MODE == 2) ? 0 : (wv & 1);

  f32x4 acc[MF][NF] = {};

  for (int kt = 0; kt < KT; ++kt) {
    const int k0 = kt * 64;
    __syncthreads();
#pragma unroll
    for (int it = 0; it < 4; ++it) {
      int rb = it * 32 + wv * 8;
      int row = rb + (lane >> 3);
      const ushort* gp;
      if constexpr (MODE == 2) {
        int b_ = mt * 128 + row;
        const ushort* src = (k0 < 256) ? A : A2;
        gp = src + (size_t)(b_ * NNODE + node) * GH + (k0 & 255) + (lane & 7) * 8 + j8;
      } else {
        gp = Ab + (size_t)row * LDA + k0 + (lane & 7) * 8 + j8;
      }
      gload16(gp, &As[rb * 64]);
    }
#pragma unroll
    for (int it = 0; it < BN / 32; ++it) {
      int rb = it * 32 + wv * 8;
      int row = rb + (lane >> 3);
      gload16(Bb + (size_t)row * LDB + k0 + (lane & 7) * 8 + j8, &Bs[rb * 64]);
    }
    __syncthreads();
#pragma unroll
    for (int kk = 0; kk < 2; ++kk) {
      const int ch8 = ((kk * 4 + (lane >> 4)) ^ (lane & 7)) * 8;   // swizzled read chunk
      bf16x8 af[MF], bfr[NF];
#pragma unroll
      for (int m = 0; m < MF; ++m) {
        int rr = wr * (MF * 16) + m * 16 + (lane & 15);
        af[m] = *reinterpret_cast<const bf16x8*>(&As[rr * 64 + ch8]);
      }
#pragma unroll
      for (int n = 0; n < NF; ++n) {
        int rr = wc * 64 + n * 16 + (lane & 15);
        bfr[n] = *reinterpret_cast<const bf16x8*>(&Bs[rr * 64 + ch8]);
      }
#pragma unroll
      for (int m = 0; m < MF; ++m)
#pragma unroll
        for (int n = 0; n < NF; ++n)
          acc[m][n] = __builtin_amdgcn_mfma_f32_16x16x32_bf16(af[m], bfr[n], acc[m][n], 0, 0, 0);
    }
  }

  const int lrow = (lane >> 4) * 4, lcol = lane & 15;
#pragma unroll
  for (int m = 0; m < MF; ++m) {
#pragma unroll
    for (int n = 0; n < NF; ++n) {
      int cc = wc * 64 + n * 16 + lcol;
#pragma unroll
      for (int rg = 0; rg < 4; ++rg) {
        int rr = wr * (MF * 16) + m * 16 + lrow + rg;
        float val = acc[m][n][rg];
        if constexpr (MODE == 0) {
          int b_ = mt * 128 + rr;
          int col = nt * 128 + cc;
          val = fmaxf(val + bias[node * GH + col], 0.f);
          obf[(size_t)br * HB + (size_t)(b_ * NNODE + node) * GH + col] = f2bf(val);
        } else if constexpr (MODE == 1) {
          int R = mt * 128 + rr;
          int col = nt * 128 + cc;
          obf[(size_t)br * HB + (size_t)R * GH + col] = f2bf(val * bias[br * NTOT + R]);
        } else if constexpr (MODE == 2) {
          int b_ = mt * 128 + rr;
          val = fmaxf(val + bias[node * DH + cc], 0.f);
          obf[(size_t)b_ * (NNODE * DH) + node * DH + cc] = f2bf(val);
        } else {
          int R = mt * 128 + rr;
          if (blockIdx.y == 0) val += bias[cc];
          atomicAdd(&of[R * OUTC + cc], val);
        }
      }
    }
  }
}

extern "C" void kernel_launch(void* const* d_in, const int* in_sizes, int n_in,
                              void* d_out, int out_size, void* d_ws, size_t ws_size,
                              hipStream_t stream) {
  const float* x1 = (const float*)d_in[0];
  const float* x2 = (const float*)d_in[1];
  const int* e1 = (const int*)d_in[2];
  const int* e2 = (const int*)d_in[3];
  const float* w3 = (const float*)d_in[4];  const float* b3 = (const float*)d_in[5];
  const float* w5 = (const float*)d_in[6];  const float* b5 = (const float*)d_in[7];
  const float* w7 = (const float*)d_in[8];  const float* b7 = (const float*)d_in[9];
  const float* Wff = (const float*)d_in[10]; const float* bff = (const float*)d_in[11];
  const float* Wg = (const float*)d_in[12];  const float* bg = (const float*)d_in[13];
  const float* Wd = (const float*)d_in[14];  const float* bd = (const float*)d_in[15];
  const float* Wfc = (const float*)d_in[16]; const float* bfc = (const float*)d_in[17];
  float* out = (float*)d_out;

  char* ws = (char*)d_ws;
  size_t off = 0;
  auto alloc = [&](size_t bytes) -> char* {
    char* p = ws + off;
    off = (off + bytes + 255) & ~(size_t)255;
    return p;
  };
  ushort* Wffb = (ushort*)alloc(19660800ull * 2);
  ushort* Wdb  = (ushort*)alloc(3276800ull * 2);
  ushort* Wfcb = (ushort*)alloc(819200ull * 2);
  ushort* Wgb  = (ushort*)alloc(65536ull * 2);
  ushort* cbuf = (ushort*)alloc(2 * CB * 2);   // both branches; later aliased as du
  ushort* h    = (ushort*)alloc(2 * HB * 2);   // both branches; later aliased as hg
  ushort* xw   = (ushort*)alloc(2 * HB * 2);   // both branches
  int* deg   = (int*)alloc(2 * NTOT * 4);
  int* offs  = (int*)alloc(2 * (NTOT + 1) * 4);
  int* curs  = (int*)alloc(2 * NTOT * 4);
  int* csr   = (int*)alloc(2 * NE * 4);
  float* nrm = (float*)alloc(2 * NTOT * 4);
  ushort* du = cbuf;  // alias: cbuf free after merged FF GEMM

  hipMemsetAsync(deg, 0, 2 * NTOT * 4, stream);
  hipMemsetAsync(out, 0, (size_t)out_size * 4, stream);

  cvt_k<<<23264, 256, 0, stream>>>(Wff, Wd, Wfc, Wg, Wffb, Wdb, Wfcb, Wgb);

  // CSR build, both edge sets in single launches
  hist_k<<<3200, 256, 0, stream>>>(e1 + NE, e2 + NE, deg);
  scan_k<<<2, 1024, 0, stream>>>(deg, offs, curs, nrm);
  fill_k<<<3200, 256, 0, stream>>>(e1, e2, curs, csr);

  // both branches per stage
  conv_k<<<3200, 256, 0, stream>>>(x1, x2, w3, b3, w5, b5, w7, b7, cbuf);
  gemm_k<0><<<800, 256, 0, stream>>>(cbuf, nullptr, Wffb, h, nullptr, bff);
  gemm_k<1><<<800, 256, 0, stream>>>(h, nullptr, Wgb, xw, nullptr, nrm);
  agg_k<<<12800, 256, 0, stream>>>(xw, offs, csr, nrm, bg, h);   // hg overwrites h

  // discrepancy FC + final FC
  gemm_k<2><<<dim3(2, 100), 256, 0, stream>>>(h, h + HB, Wdb, du, nullptr, bd);
  gemm_k<3><<<dim3(2, 25), 256, 0, stream>>>(du, nullptr, Wfcb, nullptr, out, bfc);
}

// Round 7
// 266.826 us; speedup vs baseline: 1.6542x; 1.1718x over previous
//
#include <hip/hip_runtime.h>

#define DI __device__ __forceinline__

typedef __bf16 bf16_t;
typedef bf16_t bf16x8 __attribute__((ext_vector_type(8)));
typedef float f32x4 __attribute__((ext_vector_type(4)));
typedef ushort ushort8v __attribute__((ext_vector_type(8)));

static constexpr int NNODE = 100, WIN = 128, GH = 256, DH = 64, OUTC = 128, NB = 256;
static constexpr int NTOT = NB * NNODE;   // 25600
static constexpr int NE = 409600;
static constexpr int FFK = 6 * WIN;       // 768
static constexpr size_t CB = (size_t)NNODE * NB * FFK;   // per-branch conv buf elems
static constexpr size_t HB = (size_t)NTOT * GH;          // per-branch h/xw elems
static constexpr int CVT_BLKS = 23264;    // exact: (19660800+3276800+819200+65536)/4/256

DI ushort f2bf(float f) {
  union { float f; unsigned u; } v; v.f = f;
  unsigned r = v.u + 0x7fffu + ((v.u >> 16) & 1u);
  return (ushort)(r >> 16);
}
DI float bf2f(ushort s) {
  union { unsigned u; float f; } v; v.u = ((unsigned)s) << 16; return v.f;
}

DI void gload16(const void* g, void* l) {
  __builtin_amdgcn_global_load_lds((const __attribute__((address_space(1))) void*)g,
                                   (__attribute__((address_space(3))) void*)l, 16, 0, 0);
}

// ================= device bodies =================

DI void cvt_body(int bx, const float* s0, const float* s1, const float* s2, const float* s3,
                 ushort* d0, ushort* d1, ushort* d2, ushort* d3) {
  int j = bx * 256 + threadIdx.x;   // vec4 index
  const float* s; ushort* d;
  if (j < 19660800 / 4) { s = s0; d = d0; }
  else if ((j -= 19660800 / 4) < 3276800 / 4) { s = s1; d = d1; }
  else if ((j -= 3276800 / 4) < 819200 / 4) { s = s2; d = d2; }
  else { j -= 819200 / 4; s = s3; d = d3; }
  float4 v = reinterpret_cast<const float4*>(s)[j];
  ushort4 o;
  o.x = f2bf(v.x); o.y = f2bf(v.y); o.z = f2bf(v.z); o.w = f2bf(v.w);
  reinterpret_cast<ushort4*>(d)[j] = o;
}

// hist with rank capture: rank[i] = old count of dst
DI void hist_body(int bx, const int* d1, const int* d2, int* deg, int* rank) {
  int i = bx * 256 + threadIdx.x;
  if (i < NE) rank[i] = atomicAdd(&deg[d1[i]], 1);
  else if (i < 2 * NE) rank[i] = atomicAdd(&deg[NTOT + d2[i - NE]], 1);
}

// atomic-free CSR fill using precomputed ranks
DI void fill_body(int bx, const int* e1, const int* e2, const int* offs,
                  const int* rank, int* csr) {
  int i = bx * 256 + threadIdx.x;
  if (i < NE) {
    int d = e1[NE + i];
    csr[offs[d] + rank[i]] = e1[i];
  } else if (i < 2 * NE) {
    int ii = i - NE;
    int d = e2[NE + ii];
    csr[NE + offs[NTOT + 1 + d] + rank[i]] = e2[ii];
  }
}

// 256-thread scan over one edge set (100 elems/thread, two-pass)
DI void scan_body(int set, const int* deg_, int* offs_, float* norm_) {
  const int* deg = deg_ + set * NTOT;
  int* offs = offs_ + set * (NTOT + 1);
  float* norm = norm_ + set * NTOT;
  __shared__ int part[256];
  int t = threadIdx.x;
  int base = t * 100;
  int s = 0;
  for (int j = 0; j < 100; ++j) s += deg[base + j];
  part[t] = s;
  __syncthreads();
  for (int d = 1; d < 256; d <<= 1) {
    int vv = (t >= d) ? part[t - d] : 0;
    __syncthreads();
    part[t] += vv;
    __syncthreads();
  }
  int run = (t > 0) ? part[t - 1] : 0;
  for (int j = 0; j < 100; ++j) {
    int dv = deg[base + j];
    offs[base + j] = run;
    norm[base + j] = rsqrtf((float)(dv + 1));
    run += dv;
  }
  if (t == 255) offs[NTOT] = part[255];
}

DI void conv_body(int bx, const float* x1, const float* x2,
                  const float* w3, const float* b3, const float* w5, const float* b5,
                  const float* w7, const float* b7, ushort* c) {
  const int t = threadIdx.x;
  const int rowi = t >> 4;
  const int idx = t & 15;
  int r = bx * 16 + rowi;
  int br = r >= NTOT;
  int rr = r - br * NTOT;
  const float* x = br ? x2 : x1;
  int b = rr / 100, node = rr - b * 100;

  __shared__ float xs[16][136];
  const int w0 = idx * 8;
  float4 v0 = *reinterpret_cast<const float4*>(x + (size_t)rr * WIN + w0);
  float4 v1 = *reinterpret_cast<const float4*>(x + (size_t)rr * WIN + w0 + 4);
  *reinterpret_cast<float4*>(&xs[rowi][4 + w0]) = v0;
  *reinterpret_cast<float4*>(&xs[rowi][4 + w0 + 4]) = v1;
  if (idx == 0) { xs[rowi][0] = 0.f; xs[rowi][1] = 0.f; xs[rowi][2] = 0.f; xs[rowi][3] = 0.f; }
  if (idx == 15) { xs[rowi][132] = 0.f; xs[rowi][133] = 0.f; xs[rowi][134] = 0.f; xs[rowi][135] = 0.f; }
  __syncthreads();

  float xv[14];
#pragma unroll
  for (int j = 0; j < 14; ++j) xv[j] = xs[rowi][1 + w0 + j];

  const float* W3 = w3 + node * 6;  const float* B3 = b3 + node * 2;
  const float* W5 = w5 + node * 10; const float* B5 = b5 + node * 2;
  const float* W7 = w7 + node * 14; const float* B7 = b7 + node * 2;
  ushort* out = c + (size_t)br * CB + (size_t)(node * NB + b) * FFK + w0;

#pragma unroll
  for (int ch = 0; ch < 2; ++ch) {
    float k3[3], k5[5], k7[7];
#pragma unroll
    for (int j = 0; j < 3; ++j) k3[j] = W3[ch * 3 + j];
#pragma unroll
    for (int j = 0; j < 5; ++j) k5[j] = W5[ch * 5 + j];
#pragma unroll
    for (int j = 0; j < 7; ++j) k7[j] = W7[ch * 7 + j];
    float bb3 = B3[ch], bb5 = B5[ch], bb7 = B7[ch];
    ushort8v o3, o5, o7;
#pragma unroll
    for (int p = 0; p < 8; ++p) {
      float a3 = bb3, a5 = bb5, a7 = bb7;
#pragma unroll
      for (int j = 0; j < 3; ++j) a3 += k3[j] * xv[p + 2 + j];
#pragma unroll
      for (int j = 0; j < 5; ++j) a5 += k5[j] * xv[p + 1 + j];
#pragma unroll
      for (int j = 0; j < 7; ++j) a7 += k7[j] * xv[p + j];
      o3[p] = f2bf(fmaxf(a3, 0.f));
      o5[p] = f2bf(fmaxf(a5, 0.f));
      o7[p] = f2bf(fmaxf(a7, 0.f));
    }
    *reinterpret_cast<ushort8v*>(out + (0 + ch) * WIN) = o3;
    *reinterpret_cast<ushort8v*>(out + (2 + ch) * WIN) = o5;
    *reinterpret_cast<ushort8v*>(out + (4 + ch) * WIN) = o7;
  }
}

// ---------- BT GEMM body (XOR-swizzled LDS, see R5 notes) ----------
template <int MODE>
DI void gemm_body(int bx, int by, const ushort* __restrict__ A, const ushort* __restrict__ A2,
                  const ushort* __restrict__ Bm, ushort* __restrict__ obf,
                  float* __restrict__ of, const float* __restrict__ bias) {
  constexpr int BN = (MODE == 2) ? 64 : 128;
  constexpr int KT = (MODE == 0) ? 12 : (MODE == 1) ? 4 : (MODE == 2) ? 8 : 4;
  constexpr int LDA = (MODE == 0) ? 768 : (MODE == 1) ? 256 : (MODE == 2) ? 256 : 6400;
  constexpr int LDB = (MODE == 0) ? 768 : (MODE == 1) ? 256 : (MODE == 2) ? 512 : 6400;
  constexpr int MF = (MODE == 2) ? 2 : 4;
  constexpr int NF = 4;

  __shared__ ushort As[128 * 64];
  __shared__ ushort Bs[BN * 64];

  const int tid = threadIdx.x, wv = tid >> 6, lane = tid & 63;
  const int j8 = (((lane & 7) ^ (lane >> 3)) - (lane & 7)) * 8;  // source pre-swizzle delta

  int mt = 0, nt = 0, node = 0, kbase = 0, br = 0;
  if constexpr (MODE == 0) {
    int h = bx;                            // 0..799, XCD-pair swizzle
    int s = (h & 7) * 100 + (h >> 3);
    nt = s & 1; int rest = s >> 1;
    mt = rest & 1; int yy = rest >> 1;
    br = yy >= 100; node = yy - br * 100;
  } else if constexpr (MODE == 1) {
    int h = bx;
    int s = (h & 7) * 100 + (h >> 3);
    nt = s & 1; int rest = s >> 1;
    br = rest >= 200; mt = rest - br * 200;
  } else if constexpr (MODE == 2) { mt = bx; node = by; }
  else { mt = bx; kbase = by * 256; }

  const ushort* Ab = nullptr; const ushort* Bb = nullptr;
  if constexpr (MODE == 0) { Ab = A + (size_t)br * CB + (size_t)node * (NB * FFK) + (size_t)mt * 128 * FFK;
                             Bb = Bm + (size_t)node * (GH * FFK) + (size_t)nt * 128 * FFK; }
  else if constexpr (MODE == 1) { Ab = A + (size_t)br * HB + (size_t)mt * 128 * GH;
                                  Bb = Bm + (size_t)nt * 128 * GH; }
  else if constexpr (MODE == 2) { Bb = Bm + (size_t)node * (DH * 512); }
  else { Ab = A + (size_t)mt * 128 * 6400 + kbase; Bb = Bm + kbase; }

  const int wr = (MODE == 2) ? wv : (wv >> 1);
  const int wc = (MODE == 2) ? 0 : (wv & 1);

  f32x4 acc[MF][NF] = {};

  for (int kt = 0; kt < KT; ++kt) {
    const int k0 = kt * 64;
    __syncthreads();
#pragma unroll
    for (int it = 0; it < 4; ++it) {
      int rb = it * 32 + wv * 8;
      int row = rb + (lane >> 3);
      const ushort* gp;
      if constexpr (MODE == 2) {
        int b_ = mt * 128 + row;
        const ushort* src = (k0 < 256) ? A : A2;
        gp = src + (size_t)(b_ * NNODE + node) * GH + (k0 & 255) + (lane & 7) * 8 + j8;
      } else {
        gp = Ab + (size_t)row * LDA + k0 + (lane & 7) * 8 + j8;
      }
      gload16(gp, &As[rb * 64]);
    }
#pragma unroll
    for (int it = 0; it < BN / 32; ++it) {
      int rb = it * 32 + wv * 8;
      int row = rb + (lane >> 3);
      gload16(Bb + (size_t)row * LDB + k0 + (lane & 7) * 8 + j8, &Bs[rb * 64]);
    }
    __syncthreads();
#pragma unroll
    for (int kk = 0; kk < 2; ++kk) {
      const int ch8 = ((kk * 4 + (lane >> 4)) ^ (lane & 7)) * 8;   // swizzled read chunk
      bf16x8 af[MF], bfr[NF];
#pragma unroll
      for (int m = 0; m < MF; ++m) {
        int rr = wr * (MF * 16) + m * 16 + (lane & 15);
        af[m] = *reinterpret_cast<const bf16x8*>(&As[rr * 64 + ch8]);
      }
#pragma unroll
      for (int n = 0; n < NF; ++n) {
        int rr = wc * 64 + n * 16 + (lane & 15);
        bfr[n] = *reinterpret_cast<const bf16x8*>(&Bs[rr * 64 + ch8]);
      }
#pragma unroll
      for (int m = 0; m < MF; ++m)
#pragma unroll
        for (int n = 0; n < NF; ++n)
          acc[m][n] = __builtin_amdgcn_mfma_f32_16x16x32_bf16(af[m], bfr[n], acc[m][n], 0, 0, 0);
    }
  }

  const int lrow = (lane >> 4) * 4, lcol = lane & 15;
#pragma unroll
  for (int m = 0; m < MF; ++m) {
#pragma unroll
    for (int n = 0; n < NF; ++n) {
      int cc = wc * 64 + n * 16 + lcol;
#pragma unroll
      for (int rg = 0; rg < 4; ++rg) {
        int rr = wr * (MF * 16) + m * 16 + lrow + rg;
        float val = acc[m][n][rg];
        if constexpr (MODE == 0) {
          int b_ = mt * 128 + rr;
          int col = nt * 128 + cc;
          val = fmaxf(val + bias[node * GH + col], 0.f);
          obf[(size_t)br * HB + (size_t)(b_ * NNODE + node) * GH + col] = f2bf(val);
        } else if constexpr (MODE == 1) {
          int R = mt * 128 + rr;
          int col = nt * 128 + cc;
          obf[(size_t)br * HB + (size_t)R * GH + col] = f2bf(val * bias[br * NTOT + R]);
        } else if constexpr (MODE == 2) {
          int b_ = mt * 128 + rr;
          val = fmaxf(val + bias[node * DH + cc], 0.f);
          obf[(size_t)b_ * (NNODE * DH) + node * DH + cc] = f2bf(val);
        } else {
          int R = mt * 128 + rr;
          if (by == 0) val += bias[cc];
          atomicAdd(&of[R * OUTC + cc], val);
        }
      }
    }
  }
}

// ================= fused launch kernels =================

__global__ __launch_bounds__(256) void fused1_k(
    const float* __restrict__ Wff, const float* __restrict__ Wd,
    const float* __restrict__ Wfc, const float* __restrict__ Wg,
    ushort* __restrict__ Wffb, ushort* __restrict__ Wdb,
    ushort* __restrict__ Wfcb, ushort* __restrict__ Wgb,
    const int* __restrict__ e1d, const int* __restrict__ e2d,
    int* __restrict__ deg, int* __restrict__ rank) {
  if ((int)blockIdx.x < CVT_BLKS) cvt_body(blockIdx.x, Wff, Wd, Wfc, Wg, Wffb, Wdb, Wfcb, Wgb);
  else hist_body(blockIdx.x - CVT_BLKS, e1d, e2d, deg, rank);
}

__global__ __launch_bounds__(256) void fused2_k(
    const float* __restrict__ x1, const float* __restrict__ x2,
    const float* __restrict__ w3, const float* __restrict__ b3,
    const float* __restrict__ w5, const float* __restrict__ b5,
    const float* __restrict__ w7, const float* __restrict__ b7,
    ushort* __restrict__ c,
    const int* __restrict__ deg, int* __restrict__ offs, float* __restrict__ nrm) {
  if ((int)blockIdx.x < 3200)
    conv_body(blockIdx.x, x1, x2, w3, b3, w5, b5, w7, b7, c);
  else
    scan_body(blockIdx.x - 3200, deg, offs, nrm);
}

__global__ __launch_bounds__(256) void fused3_k(
    const ushort* __restrict__ cbuf, const ushort* __restrict__ Wffb,
    ushort* __restrict__ h, const float* __restrict__ bff,
    const int* __restrict__ e1, const int* __restrict__ e2,
    const int* __restrict__ offs, const int* __restrict__ rank, int* __restrict__ csr) {
  if ((int)blockIdx.x < 800)
    gemm_body<0>(blockIdx.x, 0, cbuf, nullptr, Wffb, h, nullptr, bff);
  else
    fill_body(blockIdx.x - 800, e1, e2, offs, rank, csr);
}

template <int MODE>
__global__ __launch_bounds__(256) void gemm_k(const ushort* __restrict__ A, const ushort* __restrict__ A2,
                                              const ushort* __restrict__ Bm, ushort* __restrict__ obf,
                                              float* __restrict__ of, const float* __restrict__ bias) {
  gemm_body<MODE>(blockIdx.x, blockIdx.y, A, A2, Bm, obf, of, bias);
}

// ---------- GCN aggregation, both branches: one wave per dst node ----------
__global__ __launch_bounds__(256) void agg_k(const ushort* __restrict__ xw_, const int* __restrict__ offs_,
                                             const int* __restrict__ csr_, const float* __restrict__ norm_,
                                             const float* __restrict__ bg, ushort* __restrict__ hg_) {
  int idx = blockIdx.x * 4 + (threadIdx.x >> 6);   // [0, 51200)
  int br = idx >= NTOT;
  int v = idx - br * NTOT;
  const ushort* xw = xw_ + (size_t)br * HB;
  const int* offs = offs_ + br * (NTOT + 1);
  const int* csr = csr_ + br * NE;
  const float* norm = norm_ + br * NTOT;
  ushort* hg = hg_ + (size_t)br * HB;

  int lane = threadIdx.x & 63;
  int half = lane >> 5;
  int colb = (lane & 31) * 8;
  const ushort* base = xw + colb;

  float a[8] = {0.f, 0.f, 0.f, 0.f, 0.f, 0.f, 0.f, 0.f};
  if (half == 0) {
    ushort8v q = *reinterpret_cast<const ushort8v*>(base + (size_t)v * GH);
#pragma unroll
    for (int i = 0; i < 8; ++i) a[i] += bf2f(q[i]);
  }
  int e0 = offs[v], e1 = offs[v + 1];
  int j = e0 + half;
  for (; j + 6 < e1; j += 8) {
    int s0 = csr[j], s1 = csr[j + 2], s2 = csr[j + 4], s3 = csr[j + 6];
    ushort8v q0 = *reinterpret_cast<const ushort8v*>(base + (size_t)s0 * GH);
    ushort8v q1 = *reinterpret_cast<const ushort8v*>(base + (size_t)s1 * GH);
    ushort8v q2 = *reinterpret_cast<const ushort8v*>(base + (size_t)s2 * GH);
    ushort8v q3 = *reinterpret_cast<const ushort8v*>(base + (size_t)s3 * GH);
#pragma unroll
    for (int i = 0; i < 8; ++i)
      a[i] += (bf2f(q0[i]) + bf2f(q1[i])) + (bf2f(q2[i]) + bf2f(q3[i]));
  }
  for (; j + 2 < e1; j += 4) {
    int s0 = csr[j], s1 = csr[j + 2];
    ushort8v q0 = *reinterpret_cast<const ushort8v*>(base + (size_t)s0 * GH);
    ushort8v q1 = *reinterpret_cast<const ushort8v*>(base + (size_t)s1 * GH);
#pragma unroll
    for (int i = 0; i < 8; ++i) a[i] += bf2f(q0[i]) + bf2f(q1[i]);
  }
  if (j < e1) {
    int s0 = csr[j];
    ushort8v q0 = *reinterpret_cast<const ushort8v*>(base + (size_t)s0 * GH);
#pragma unroll
    for (int i = 0; i < 8; ++i) a[i] += bf2f(q0[i]);
  }
#pragma unroll
  for (int i = 0; i < 8; ++i) a[i] += __shfl_xor(a[i], 32);

  if (half == 0) {
    float nv = norm[v];
    float4 bb0 = *reinterpret_cast<const float4*>(bg + colb);
    float4 bb1 = *reinterpret_cast<const float4*>(bg + colb + 4);
    ushort8v o;
    o[0] = f2bf(fmaxf(nv * a[0] + bb0.x, 0.f));
    o[1] = f2bf(fmaxf(nv * a[1] + bb0.y, 0.f));
    o[2] = f2bf(fmaxf(nv * a[2] + bb0.z, 0.f));
    o[3] = f2bf(fmaxf(nv * a[3] + bb0.w, 0.f));
    o[4] = f2bf(fmaxf(nv * a[4] + bb1.x, 0.f));
    o[5] = f2bf(fmaxf(nv * a[5] + bb1.y, 0.f));
    o[6] = f2bf(fmaxf(nv * a[6] + bb1.z, 0.f));
    o[7] = f2bf(fmaxf(nv * a[7] + bb1.w, 0.f));
    *reinterpret_cast<ushort8v*>(hg + (size_t)v * GH + colb) = o;
  }
}

extern "C" void kernel_launch(void* const* d_in, const int* in_sizes, int n_in,
                              void* d_out, int out_size, void* d_ws, size_t ws_size,
                              hipStream_t stream) {
  const float* x1 = (const float*)d_in[0];
  const float* x2 = (const float*)d_in[1];
  const int* e1 = (const int*)d_in[2];
  const int* e2 = (const int*)d_in[3];
  const float* w3 = (const float*)d_in[4];  const float* b3 = (const float*)d_in[5];
  const float* w5 = (const float*)d_in[6];  const float* b5 = (const float*)d_in[7];
  const float* w7 = (const float*)d_in[8];  const float* b7 = (const float*)d_in[9];
  const float* Wff = (const float*)d_in[10]; const float* bff = (const float*)d_in[11];
  const float* Wg = (const float*)d_in[12];  const float* bg = (const float*)d_in[13];
  const float* Wd = (const float*)d_in[14];  const float* bd = (const float*)d_in[15];
  const float* Wfc = (const float*)d_in[16]; const float* bfc = (const float*)d_in[17];
  float* out = (float*)d_out;

  char* ws = (char*)d_ws;
  size_t off = 0;
  auto alloc = [&](size_t bytes) -> char* {
    char* p = ws + off;
    off = (off + bytes + 255) & ~(size_t)255;
    return p;
  };
  ushort* Wffb = (ushort*)alloc(19660800ull * 2);
  ushort* Wdb  = (ushort*)alloc(3276800ull * 2);
  ushort* Wfcb = (ushort*)alloc(819200ull * 2);
  ushort* Wgb  = (ushort*)alloc(65536ull * 2);
  ushort* cbuf = (ushort*)alloc(2 * CB * 2);   // both branches; later aliased as du
  ushort* h    = (ushort*)alloc(2 * HB * 2);   // both branches; later aliased as hg
  ushort* xw   = (ushort*)alloc(2 * HB * 2);   // both branches
  int* deg   = (int*)alloc(2 * NTOT * 4);
  int* offs  = (int*)alloc(2 * (NTOT + 1) * 4);
  int* rank  = (int*)alloc(2 * NE * 4);
  int* csr   = (int*)alloc(2 * NE * 4);
  float* nrm = (float*)alloc(2 * NTOT * 4);
  ushort* du = cbuf;  // alias: cbuf free after FF GEMM

  hipMemsetAsync(deg, 0, 2 * NTOT * 4, stream);
  hipMemsetAsync(out, 0, (size_t)out_size * 4, stream);

  // F1: weight cvt || degree-histogram-with-rank
  fused1_k<<<CVT_BLKS + 3200, 256, 0, stream>>>(Wff, Wd, Wfc, Wg, Wffb, Wdb, Wfcb, Wgb,
                                                e1 + NE, e2 + NE, deg, rank);
  // F2: multiscale conv || offset scan
  fused2_k<<<3202, 256, 0, stream>>>(x1, x2, w3, b3, w5, b5, w7, b7, cbuf, deg, offs, nrm);
  // F3: FF GEMM || atomic-free CSR fill
  fused3_k<<<4000, 256, 0, stream>>>(cbuf, Wffb, h, bff, e1, e2, offs, rank, csr);

  gemm_k<1><<<800, 256, 0, stream>>>(h, nullptr, Wgb, xw, nullptr, nrm);
  agg_k<<<12800, 256, 0, stream>>>(xw, offs, csr, nrm, bg, h);   // hg overwrites h

  gemm_k<2><<<dim3(2, 100), 256, 0, stream>>>(h, h + HB, Wdb, du, nullptr, bd);
  gemm_k<3><<<dim3(2, 25), 256, 0, stream>>>(du, nullptr, Wfcb, nullptr, out, bfc);
}

// Round 8
// 264.840 us; speedup vs baseline: 1.6666x; 1.0075x over previous
//
#include <hip/hip_runtime.h>

#define DI __device__ __forceinline__

typedef __bf16 bf16_t;
typedef bf16_t bf16x8 __attribute__((ext_vector_type(8)));
typedef float f32x4 __attribute__((ext_vector_type(4)));
typedef ushort ushort8v __attribute__((ext_vector_type(8)));

static constexpr int NNODE = 100, WIN = 128, GH = 256, DH = 64, OUTC = 128, NB = 256;
static constexpr int NTOT = NB * NNODE;   // 25600
static constexpr int NE = 409600;
static constexpr int FFK = 6 * WIN;       // 768
static constexpr size_t CB = (size_t)NNODE * NB * FFK;   // per-branch conv buf elems
static constexpr size_t HB = (size_t)NTOT * GH;          // per-branch h/xw elems
static constexpr int CVT_BLKS = 23264;    // exact: (19660800+3276800+819200+65536)/4/256

DI ushort f2bf(float f) {
  union { float f; unsigned u; } v; v.f = f;
  unsigned r = v.u + 0x7fffu + ((v.u >> 16) & 1u);
  return (ushort)(r >> 16);
}
DI float bf2f(ushort s) {
  union { unsigned u; float f; } v; v.u = ((unsigned)s) << 16; return v.f;
}

DI void gload16(const void* g, void* l) {
  __builtin_amdgcn_global_load_lds((const __attribute__((address_space(1))) void*)g,
                                   (__attribute__((address_space(3))) void*)l, 16, 0, 0);
}

// ================= device bodies =================

DI void cvt_body(int bx, const float* s0, const float* s1, const float* s2, const float* s3,
                 ushort* d0, ushort* d1, ushort* d2, ushort* d3) {
  int j = bx * 256 + threadIdx.x;   // vec4 index
  const float* s; ushort* d;
  if (j < 19660800 / 4) { s = s0; d = d0; }
  else if ((j -= 19660800 / 4) < 3276800 / 4) { s = s1; d = d1; }
  else if ((j -= 3276800 / 4) < 819200 / 4) { s = s2; d = d2; }
  else { j -= 819200 / 4; s = s3; d = d3; }
  float4 v = reinterpret_cast<const float4*>(s)[j];
  ushort4 o;
  o.x = f2bf(v.x); o.y = f2bf(v.y); o.z = f2bf(v.z); o.w = f2bf(v.w);
  reinterpret_cast<ushort4*>(d)[j] = o;
}

// hist with rank capture: rank[i] = old count of dst
DI void hist_body(int bx, const int* d1, const int* d2, int* deg, int* rank) {
  int i = bx * 256 + threadIdx.x;
  if (i < NE) rank[i] = atomicAdd(&deg[d1[i]], 1);
  else if (i < 2 * NE) rank[i] = atomicAdd(&deg[NTOT + d2[i - NE]], 1);
}

// atomic-free CSR fill using precomputed ranks
DI void fill_body(int bx, const int* e1, const int* e2, const int* offs,
                  const int* rank, int* csr) {
  int i = bx * 256 + threadIdx.x;
  if (i < NE) {
    int d = e1[NE + i];
    csr[offs[d] + rank[i]] = e1[i];
  } else if (i < 2 * NE) {
    int ii = i - NE;
    int d = e2[NE + ii];
    csr[NE + offs[NTOT + 1 + d] + rank[i]] = e2[ii];
  }
}

// 256-thread scan over one edge set (100 elems/thread, two-pass)
DI void scan_body(int set, const int* deg_, int* offs_, float* norm_) {
  const int* deg = deg_ + set * NTOT;
  int* offs = offs_ + set * (NTOT + 1);
  float* norm = norm_ + set * NTOT;
  __shared__ int part[256];
  int t = threadIdx.x;
  int base = t * 100;
  int s = 0;
  for (int j = 0; j < 100; ++j) s += deg[base + j];
  part[t] = s;
  __syncthreads();
  for (int d = 1; d < 256; d <<= 1) {
    int vv = (t >= d) ? part[t - d] : 0;
    __syncthreads();
    part[t] += vv;
    __syncthreads();
  }
  int run = (t > 0) ? part[t - 1] : 0;
  for (int j = 0; j < 100; ++j) {
    int dv = deg[base + j];
    offs[base + j] = run;
    norm[base + j] = rsqrtf((float)(dv + 1));
    run += dv;
  }
  if (t == 255) offs[NTOT] = part[255];
}

DI void conv_body(int bx, const float* x1, const float* x2,
                  const float* w3, const float* b3, const float* w5, const float* b5,
                  const float* w7, const float* b7, ushort* c) {
  const int t = threadIdx.x;
  const int rowi = t >> 4;
  const int idx = t & 15;
  int r = bx * 16 + rowi;
  int br = r >= NTOT;
  int rr = r - br * NTOT;
  const float* x = br ? x2 : x1;
  int b = rr / 100, node = rr - b * 100;

  __shared__ float xs[16][136];
  const int w0 = idx * 8;
  float4 v0 = *reinterpret_cast<const float4*>(x + (size_t)rr * WIN + w0);
  float4 v1 = *reinterpret_cast<const float4*>(x + (size_t)rr * WIN + w0 + 4);
  *reinterpret_cast<float4*>(&xs[rowi][4 + w0]) = v0;
  *reinterpret_cast<float4*>(&xs[rowi][4 + w0 + 4]) = v1;
  if (idx == 0) { xs[rowi][0] = 0.f; xs[rowi][1] = 0.f; xs[rowi][2] = 0.f; xs[rowi][3] = 0.f; }
  if (idx == 15) { xs[rowi][132] = 0.f; xs[rowi][133] = 0.f; xs[rowi][134] = 0.f; xs[rowi][135] = 0.f; }
  __syncthreads();

  float xv[14];
#pragma unroll
  for (int j = 0; j < 14; ++j) xv[j] = xs[rowi][1 + w0 + j];

  const float* W3 = w3 + node * 6;  const float* B3 = b3 + node * 2;
  const float* W5 = w5 + node * 10; const float* B5 = b5 + node * 2;
  const float* W7 = w7 + node * 14; const float* B7 = b7 + node * 2;
  ushort* out = c + (size_t)br * CB + (size_t)(node * NB + b) * FFK + w0;

#pragma unroll
  for (int ch = 0; ch < 2; ++ch) {
    float k3[3], k5[5], k7[7];
#pragma unroll
    for (int j = 0; j < 3; ++j) k3[j] = W3[ch * 3 + j];
#pragma unroll
    for (int j = 0; j < 5; ++j) k5[j] = W5[ch * 5 + j];
#pragma unroll
    for (int j = 0; j < 7; ++j) k7[j] = W7[ch * 7 + j];
    float bb3 = B3[ch], bb5 = B5[ch], bb7 = B7[ch];
    ushort8v o3, o5, o7;
#pragma unroll
    for (int p = 0; p < 8; ++p) {
      float a3 = bb3, a5 = bb5, a7 = bb7;
#pragma unroll
      for (int j = 0; j < 3; ++j) a3 += k3[j] * xv[p + 2 + j];
#pragma unroll
      for (int j = 0; j < 5; ++j) a5 += k5[j] * xv[p + 1 + j];
#pragma unroll
      for (int j = 0; j < 7; ++j) a7 += k7[j] * xv[p + j];
      o3[p] = f2bf(fmaxf(a3, 0.f));
      o5[p] = f2bf(fmaxf(a5, 0.f));
      o7[p] = f2bf(fmaxf(a7, 0.f));
    }
    *reinterpret_cast<ushort8v*>(out + (0 + ch) * WIN) = o3;
    *reinterpret_cast<ushort8v*>(out + (2 + ch) * WIN) = o5;
    *reinterpret_cast<ushort8v*>(out + (4 + ch) * WIN) = o7;
  }
}

// ---------- BT GEMM body (XOR-swizzled LDS, see R5 notes) ----------
template <int MODE>
DI void gemm_body(int bx, int by, const ushort* __restrict__ A, const ushort* __restrict__ A2,
                  const ushort* __restrict__ Bm, ushort* __restrict__ obf,
                  float* __restrict__ of, const float* __restrict__ bias) {
  constexpr int BN = (MODE == 2) ? 64 : 128;
  constexpr int KT = (MODE == 0) ? 12 : (MODE == 1) ? 4 : (MODE == 2) ? 8 : 4;
  constexpr int LDA = (MODE == 0) ? 768 : (MODE == 1) ? 256 : (MODE == 2) ? 256 : 6400;
  constexpr int LDB = (MODE == 0) ? 768 : (MODE == 1) ? 256 : (MODE == 2) ? 512 : 6400;
  constexpr int MF = (MODE == 2) ? 2 : 4;
  constexpr int NF = 4;

  __shared__ ushort As[128 * 64];
  __shared__ ushort Bs[BN * 64];

  const int tid = threadIdx.x, wv = tid >> 6, lane = tid & 63;
  const int j8 = (((lane & 7) ^ (lane >> 3)) - (lane & 7)) * 8;  // source pre-swizzle delta

  int mt = 0, nt = 0, node = 0, kbase = 0, br = 0;
  if constexpr (MODE == 0) {
    int h = bx;                            // 0..799, XCD-pair swizzle
    int s = (h & 7) * 100 + (h >> 3);
    nt = s & 1; int rest = s >> 1;
    mt = rest & 1; int yy = rest >> 1;
    br = yy >= 100; node = yy - br * 100;
  } else if constexpr (MODE == 1) {
    int h = bx;
    int s = (h & 7) * 100 + (h >> 3);
    nt = s & 1; int rest = s >> 1;
    br = rest >= 200; mt = rest - br * 200;
  } else if constexpr (MODE == 2) { mt = bx; node = by; }
  else { mt = bx; kbase = by * 256; }

  const ushort* Ab = nullptr; const ushort* Bb = nullptr;
  if constexpr (MODE == 0) { Ab = A + (size_t)br * CB + (size_t)node * (NB * FFK) + (size_t)mt * 128 * FFK;
                             Bb = Bm + (size_t)node * (GH * FFK) + (size_t)nt * 128 * FFK; }
  else if constexpr (MODE == 1) { Ab = A + (size_t)br * HB + (size_t)mt * 128 * GH;
                                  Bb = Bm + (size_t)nt * 128 * GH; }
  else if constexpr (MODE == 2) { Bb = Bm + (size_t)node * (DH * 512); }
  else { Ab = A + (size_t)mt * 128 * 6400 + kbase; Bb = Bm + kbase; }

  const int wr = (MODE == 2) ? wv : (wv >> 1);
  const int wc = (MODE == 2) ? 0 : (wv & 1);

  f32x4 acc[MF][NF] = {};

  for (int kt = 0; kt < KT; ++kt) {
    const int k0 = kt * 64;
    __syncthreads();
#pragma unroll
    for (int it = 0; it < 4; ++it) {
      int rb = it * 32 + wv * 8;
      int row = rb + (lane >> 3);
      const ushort* gp;
      if constexpr (MODE == 2) {
        int b_ = mt * 128 + row;
        const ushort* src = (k0 < 256) ? A : A2;
        gp = src + (size_t)(b_ * NNODE + node) * GH + (k0 & 255) + (lane & 7) * 8 + j8;
      } else {
        gp = Ab + (size_t)row * LDA + k0 + (lane & 7) * 8 + j8;
      }
      gload16(gp, &As[rb * 64]);
    }
#pragma unroll
    for (int it = 0; it < BN / 32; ++it) {
      int rb = it * 32 + wv * 8;
      int row = rb + (lane >> 3);
      gload16(Bb + (size_t)row * LDB + k0 + (lane & 7) * 8 + j8, &Bs[rb * 64]);
    }
    __syncthreads();
#pragma unroll
    for (int kk = 0; kk < 2; ++kk) {
      const int ch8 = ((kk * 4 + (lane >> 4)) ^ (lane & 7)) * 8;   // swizzled read chunk
      bf16x8 af[MF], bfr[NF];
#pragma unroll
      for (int m = 0; m < MF; ++m) {
        int rr = wr * (MF * 16) + m * 16 + (lane & 15);
        af[m] = *reinterpret_cast<const bf16x8*>(&As[rr * 64 + ch8]);
      }
#pragma unroll
      for (int n = 0; n < NF; ++n) {
        int rr = wc * 64 + n * 16 + (lane & 15);
        bfr[n] = *reinterpret_cast<const bf16x8*>(&Bs[rr * 64 + ch8]);
      }
#pragma unroll
      for (int m = 0; m < MF; ++m)
#pragma unroll
        for (int n = 0; n < NF; ++n)
          acc[m][n] = __builtin_amdgcn_mfma_f32_16x16x32_bf16(af[m], bfr[n], acc[m][n], 0, 0, 0);
    }
  }

  const int lrow = (lane >> 4) * 4, lcol = lane & 15;
#pragma unroll
  for (int m = 0; m < MF; ++m) {
#pragma unroll
    for (int n = 0; n < NF; ++n) {
      int cc = wc * 64 + n * 16 + lcol;
#pragma unroll
      for (int rg = 0; rg < 4; ++rg) {
        int rr = wr * (MF * 16) + m * 16 + lrow + rg;
        float val = acc[m][n][rg];
        if constexpr (MODE == 0) {
          int b_ = mt * 128 + rr;
          int col = nt * 128 + cc;
          val = fmaxf(val + bias[node * GH + col], 0.f);
          obf[(size_t)br * HB + (size_t)(b_ * NNODE + node) * GH + col] = f2bf(val);
        } else if constexpr (MODE == 1) {
          int R = mt * 128 + rr;
          int col = nt * 128 + cc;
          obf[(size_t)br * HB + (size_t)R * GH + col] = f2bf(val * bias[br * NTOT + R]);
        } else if constexpr (MODE == 2) {
          int b_ = mt * 128 + rr;
          val = fmaxf(val + bias[node * DH + cc], 0.f);
          obf[(size_t)b_ * (NNODE * DH) + node * DH + cc] = f2bf(val);
        } else {
          int R = mt * 128 + rr;
          if (by == 0) val += bias[cc];
          atomicAdd(&of[R * OUTC + cc], val);
        }
      }
    }
  }
}

// ================= fused launch kernels =================

// F1: [hist 3200][conv 3200][cvt 23264] — latency-bound hist first, BW work backfills
__global__ __launch_bounds__(256) void fused1_k(
    const float* __restrict__ Wff, const float* __restrict__ Wd,
    const float* __restrict__ Wfc, const float* __restrict__ Wg,
    ushort* __restrict__ Wffb, ushort* __restrict__ Wdb,
    ushort* __restrict__ Wfcb, ushort* __restrict__ Wgb,
    const int* __restrict__ e1d, const int* __restrict__ e2d,
    int* __restrict__ deg, int* __restrict__ rank,
    const float* __restrict__ x1, const float* __restrict__ x2,
    const float* __restrict__ w3, const float* __restrict__ b3,
    const float* __restrict__ w5, const float* __restrict__ b5,
    const float* __restrict__ w7, const float* __restrict__ b7,
    ushort* __restrict__ c) {
  int bx = blockIdx.x;
  if (bx < 3200) hist_body(bx, e1d, e2d, deg, rank);
  else if (bx < 6400) conv_body(bx - 3200, x1, x2, w3, b3, w5, b5, w7, b7, c);
  else cvt_body(bx - 6400, Wff, Wd, Wfc, Wg, Wffb, Wdb, Wfcb, Wgb);
}

// F2: scan only (needs completed deg)
__global__ __launch_bounds__(256) void scan_k(const int* __restrict__ deg,
                                              int* __restrict__ offs, float* __restrict__ nrm) {
  scan_body(blockIdx.x, deg, offs, nrm);
}

// F3: FF GEMM || atomic-free CSR fill
__global__ __launch_bounds__(256) void fused3_k(
    const ushort* __restrict__ cbuf, const ushort* __restrict__ Wffb,
    ushort* __restrict__ h, const float* __restrict__ bff,
    const int* __restrict__ e1, const int* __restrict__ e2,
    const int* __restrict__ offs, const int* __restrict__ rank, int* __restrict__ csr) {
  if ((int)blockIdx.x < 800)
    gemm_body<0>(blockIdx.x, 0, cbuf, nullptr, Wffb, h, nullptr, bff);
  else
    fill_body(blockIdx.x - 800, e1, e2, offs, rank, csr);
}

template <int MODE>
__global__ __launch_bounds__(256) void gemm_k(const ushort* __restrict__ A, const ushort* __restrict__ A2,
                                              const ushort* __restrict__ Bm, ushort* __restrict__ obf,
                                              float* __restrict__ of, const float* __restrict__ bias) {
  gemm_body<MODE>(blockIdx.x, blockIdx.y, A, A2, Bm, obf, of, bias);
}

// ---------- GCN aggregation, both branches: one wave per dst node ----------
__global__ __launch_bounds__(256) void agg_k(const ushort* __restrict__ xw_, const int* __restrict__ offs_,
                                             const int* __restrict__ csr_, const float* __restrict__ norm_,
                                             const float* __restrict__ bg, ushort* __restrict__ hg_) {
  int idx = blockIdx.x * 4 + (threadIdx.x >> 6);   // [0, 51200)
  int br = idx >= NTOT;
  int v = idx - br * NTOT;
  const ushort* xw = xw_ + (size_t)br * HB;
  const int* offs = offs_ + br * (NTOT + 1);
  const int* csr = csr_ + br * NE;
  const float* norm = norm_ + br * NTOT;
  ushort* hg = hg_ + (size_t)br * HB;

  int lane = threadIdx.x & 63;
  int half = lane >> 5;
  int colb = (lane & 31) * 8;
  const ushort* base = xw + colb;

  float a[8] = {0.f, 0.f, 0.f, 0.f, 0.f, 0.f, 0.f, 0.f};
  if (half == 0) {
    ushort8v q = *reinterpret_cast<const ushort8v*>(base + (size_t)v * GH);
#pragma unroll
    for (int i = 0; i < 8; ++i) a[i] += bf2f(q[i]);
  }
  int e0 = offs[v], e1 = offs[v + 1];
  int j = e0 + half;
  for (; j + 6 < e1; j += 8) {
    int s0 = csr[j], s1 = csr[j + 2], s2 = csr[j + 4], s3 = csr[j + 6];
    ushort8v q0 = *reinterpret_cast<const ushort8v*>(base + (size_t)s0 * GH);
    ushort8v q1 = *reinterpret_cast<const ushort8v*>(base + (size_t)s1 * GH);
    ushort8v q2 = *reinterpret_cast<const ushort8v*>(base + (size_t)s2 * GH);
    ushort8v q3 = *reinterpret_cast<const ushort8v*>(base + (size_t)s3 * GH);
#pragma unroll
    for (int i = 0; i < 8; ++i)
      a[i] += (bf2f(q0[i]) + bf2f(q1[i])) + (bf2f(q2[i]) + bf2f(q3[i]));
  }
  for (; j + 2 < e1; j += 4) {
    int s0 = csr[j], s1 = csr[j + 2];
    ushort8v q0 = *reinterpret_cast<const ushort8v*>(base + (size_t)s0 * GH);
    ushort8v q1 = *reinterpret_cast<const ushort8v*>(base + (size_t)s1 * GH);
#pragma unroll
    for (int i = 0; i < 8; ++i) a[i] += bf2f(q0[i]) + bf2f(q1[i]);
  }
  if (j < e1) {
    int s0 = csr[j];
    ushort8v q0 = *reinterpret_cast<const ushort8v*>(base + (size_t)s0 * GH);
#pragma unroll
    for (int i = 0; i < 8; ++i) a[i] += bf2f(q0[i]);
  }
#pragma unroll
  for (int i = 0; i < 8; ++i) a[i] += __shfl_xor(a[i], 32);

  if (half == 0) {
    float nv = norm[v];
    float4 bb0 = *reinterpret_cast<const float4*>(bg + colb);
    float4 bb1 = *reinterpret_cast<const float4*>(bg + colb + 4);
    ushort8v o;
    o[0] = f2bf(fmaxf(nv * a[0] + bb0.x, 0.f));
    o[1] = f2bf(fmaxf(nv * a[1] + bb0.y, 0.f));
    o[2] = f2bf(fmaxf(nv * a[2] + bb0.z, 0.f));
    o[3] = f2bf(fmaxf(nv * a[3] + bb0.w, 0.f));
    o[4] = f2bf(fmaxf(nv * a[4] + bb1.x, 0.f));
    o[5] = f2bf(fmaxf(nv * a[5] + bb1.y, 0.f));
    o[6] = f2bf(fmaxf(nv * a[6] + bb1.z, 0.f));
    o[7] = f2bf(fmaxf(nv * a[7] + bb1.w, 0.f));
    *reinterpret_cast<ushort8v*>(hg + (size_t)v * GH + colb) = o;
  }
}

extern "C" void kernel_launch(void* const* d_in, const int* in_sizes, int n_in,
                              void* d_out, int out_size, void* d_ws, size_t ws_size,
                              hipStream_t stream) {
  const float* x1 = (const float*)d_in[0];
  const float* x2 = (const float*)d_in[1];
  const int* e1 = (const int*)d_in[2];
  const int* e2 = (const int*)d_in[3];
  const float* w3 = (const float*)d_in[4];  const float* b3 = (const float*)d_in[5];
  const float* w5 = (const float*)d_in[6];  const float* b5 = (const float*)d_in[7];
  const float* w7 = (const float*)d_in[8];  const float* b7 = (const float*)d_in[9];
  const float* Wff = (const float*)d_in[10]; const float* bff = (const float*)d_in[11];
  const float* Wg = (const float*)d_in[12];  const float* bg = (const float*)d_in[13];
  const float* Wd = (const float*)d_in[14];  const float* bd = (const float*)d_in[15];
  const float* Wfc = (const float*)d_in[16]; const float* bfc = (const float*)d_in[17];
  float* out = (float*)d_out;

  char* ws = (char*)d_ws;
  size_t off = 0;
  auto alloc = [&](size_t bytes) -> char* {
    char* p = ws + off;
    off = (off + bytes + 255) & ~(size_t)255;
    return p;
  };
  ushort* Wffb = (ushort*)alloc(19660800ull * 2);
  ushort* Wdb  = (ushort*)alloc(3276800ull * 2);
  ushort* Wfcb = (ushort*)alloc(819200ull * 2);
  ushort* Wgb  = (ushort*)alloc(65536ull * 2);
  ushort* cbuf = (ushort*)alloc(2 * CB * 2);   // both branches; later aliased as du
  ushort* h    = (ushort*)alloc(2 * HB * 2);   // both branches; later aliased as hg
  ushort* xw   = (ushort*)alloc(2 * HB * 2);   // both branches
  int* deg   = (int*)alloc(2 * NTOT * 4);
  int* offs  = (int*)alloc(2 * (NTOT + 1) * 4);
  int* rank  = (int*)alloc(2 * NE * 4);
  int* csr   = (int*)alloc(2 * NE * 4);
  float* nrm = (float*)alloc(2 * NTOT * 4);
  ushort* du = cbuf;  // alias: cbuf free after FF GEMM

  hipMemsetAsync(deg, 0, 2 * NTOT * 4, stream);
  hipMemsetAsync(out, 0, (size_t)out_size * 4, stream);

  // F1: hist (latency) first, conv + cvt (BW) backfill
  fused1_k<<<6400 + CVT_BLKS, 256, 0, stream>>>(Wff, Wd, Wfc, Wg, Wffb, Wdb, Wfcb, Wgb,
                                                e1 + NE, e2 + NE, deg, rank,
                                                x1, x2, w3, b3, w5, b5, w7, b7, cbuf);
  // F2: offset scan (tiny)
  scan_k<<<2, 256, 0, stream>>>(deg, offs, nrm);
  // F3: FF GEMM || atomic-free CSR fill
  fused3_k<<<4000, 256, 0, stream>>>(cbuf, Wffb, h, bff, e1, e2, offs, rank, csr);

  gemm_k<1><<<800, 256, 0, stream>>>(h, nullptr, Wgb, xw, nullptr, nrm);
  agg_k<<<12800, 256, 0, stream>>>(xw, offs, csr, nrm, bg, h);   // hg overwrites h

  gemm_k<2><<<dim3(2, 100), 256, 0, stream>>>(h, h + HB, Wdb, du, nullptr, bd);
  gemm_k<3><<<dim3(2, 25), 256, 0, stream>>>(du, nullptr, Wfcb, nullptr, out, bfc);
}

// Round 9
// 252.102 us; speedup vs baseline: 1.7508x; 1.0505x over previous
//
#include <hip/hip_runtime.h>

#define DI __device__ __forceinline__

typedef __bf16 bf16_t;
typedef bf16_t bf16x8 __attribute__((ext_vector_type(8)));
typedef float f32x4 __attribute__((ext_vector_type(4)));
typedef ushort ushort8v __attribute__((ext_vector_type(8)));

static constexpr int NNODE = 100, WIN = 128, GH = 256, DH = 64, OUTC = 128, NB = 256;
static constexpr int NTOT = NB * NNODE;   // 25600
static constexpr int NE = 409600;
static constexpr int FFK = 6 * WIN;       // 768
static constexpr size_t CB = (size_t)NNODE * NB * FFK;
static constexpr size_t HB = (size_t)NTOT * GH;
static constexpr int CVT_BLKS = 23264;
static constexpr int NSEG = 64, SEGE = NE / NSEG;      // 64 segs x 6400 edges
static constexpr int NPK = NTOT / 2;                    // 12800 packed counters

DI ushort f2bf(float f) {
  union { float f; unsigned u; } v; v.f = f;
  unsigned r = v.u + 0x7fffu + ((v.u >> 16) & 1u);
  return (ushort)(r >> 16);
}
DI float bf2f(ushort s) {
  union { unsigned u; float f; } v; v.u = ((unsigned)s) << 16; return v.f;
}

DI void gload16(const void* g, void* l) {
  __builtin_amdgcn_global_load_lds((const __attribute__((address_space(1))) void*)g,
                                   (__attribute__((address_space(3))) void*)l, 16, 0, 0);
}

// ================= device bodies =================

DI void cvt_body(int bx, const float* s0, const float* s1, const float* s2, const float* s3,
                 ushort* d0, ushort* d1, ushort* d2, ushort* d3) {
  int j = bx * 256 + threadIdx.x;   // vec4 index
  const float* s; ushort* d;
  if (j < 19660800 / 4) { s = s0; d = d0; }
  else if ((j -= 19660800 / 4) < 3276800 / 4) { s = s1; d = d1; }
  else if ((j -= 3276800 / 4) < 819200 / 4) { s = s2; d = d2; }
  else { j -= 819200 / 4; s = s3; d = d3; }
  float4 v = reinterpret_cast<const float4*>(s)[j];
  ushort4 o;
  o.x = f2bf(v.x); o.y = f2bf(v.y); o.z = f2bf(v.z); o.w = f2bf(v.w);
  reinterpret_cast<ushort4*>(d)[j] = o;
}

// LDS-privatized segmented histogram with rank capture (NO global atomics).
// Block handles (set, seg); cnt = packed dual-ushort counters for 25600 dsts.
DI void histseg_body(int bx, const int* e1d, const int* e2d,
                     ushort* rank_local, uint* segcnt, uint* cnt /*LDS, 12800*/) {
  int set = bx & 1, seg = bx >> 1;
  int tid = threadIdx.x;
#pragma unroll
  for (int k = 0; k < NPK / 256; ++k) cnt[tid + k * 256] = 0;
  __syncthreads();
  const int* dstp = (set ? e2d : e1d) + seg * SEGE;
  ushort* rl = rank_local + set * NE + seg * SEGE;
#pragma unroll
  for (int k = 0; k < SEGE / 256; ++k) {
    int i = k * 256 + tid;
    int d = dstp[i];
    uint sh = (d & 1) * 16;
    uint old = atomicAdd(&cnt[d >> 1], 1u << sh);
    rl[i] = (ushort)((old >> sh) & 0xffffu);
  }
  __syncthreads();
  uint* sc = segcnt + (size_t)(set * NSEG + seg) * NPK;
#pragma unroll
  for (int k = 0; k < NPK / 256; ++k) sc[tid + k * 256] = cnt[tid + k * 256];
}

// atomic-free CSR fill using segment base + local rank
DI void fill_body(int bx, const int* e1, const int* e2, const int* offs,
                  const ushort* rank_local, const uint* segbase, int* csr) {
  int i = bx * 256 + threadIdx.x;          // [0, 2*NE)
  int set = i >= NE;
  int ii = i - set * NE;
  const int* e = set ? e2 : e1;
  int d = e[NE + ii];
  int seg = ii / SEGE;
  uint b32 = segbase[(size_t)(set * NSEG + seg) * NPK + (d >> 1)];
  int base = (b32 >> ((d & 1) * 16)) & 0xffff;
  int pos = offs[set * (NTOT + 1) + d] + base + rank_local[i];
  csr[set * NE + pos] = e[ii];
}

// 256-thread scan over one edge set (100 elems/thread, two-pass)
DI void scan_body(int set, const int* deg_, int* offs_, float* norm_) {
  const int* deg = deg_ + set * NTOT;
  int* offs = offs_ + set * (NTOT + 1);
  float* norm = norm_ + set * NTOT;
  __shared__ int part[256];
  int t = threadIdx.x;
  int base = t * 100;
  int s = 0;
  for (int j = 0; j < 100; ++j) s += deg[base + j];
  part[t] = s;
  __syncthreads();
  for (int d = 1; d < 256; d <<= 1) {
    int vv = (t >= d) ? part[t - d] : 0;
    __syncthreads();
    part[t] += vv;
    __syncthreads();
  }
  int run = (t > 0) ? part[t - 1] : 0;
  for (int j = 0; j < 100; ++j) {
    int dv = deg[base + j];
    offs[base + j] = run;
    norm[base + j] = rsqrtf((float)(dv + 1));
    run += dv;
  }
  if (t == 255) offs[NTOT] = part[255];
}

DI void conv_body(int bx, const float* x1, const float* x2,
                  const float* w3, const float* b3, const float* w5, const float* b5,
                  const float* w7, const float* b7, ushort* c, float* xs /*LDS [16][136]*/) {
  const int t = threadIdx.x;
  const int rowi = t >> 4;
  const int idx = t & 15;
  int r = bx * 16 + rowi;
  int br = r >= NTOT;
  int rr = r - br * NTOT;
  const float* x = br ? x2 : x1;
  int b = rr / 100, node = rr - b * 100;

  float* row = xs + rowi * 136;
  const int w0 = idx * 8;
  float4 v0 = *reinterpret_cast<const float4*>(x + (size_t)rr * WIN + w0);
  float4 v1 = *reinterpret_cast<const float4*>(x + (size_t)rr * WIN + w0 + 4);
  *reinterpret_cast<float4*>(&row[4 + w0]) = v0;
  *reinterpret_cast<float4*>(&row[4 + w0 + 4]) = v1;
  if (idx == 0) { row[0] = 0.f; row[1] = 0.f; row[2] = 0.f; row[3] = 0.f; }
  if (idx == 15) { row[132] = 0.f; row[133] = 0.f; row[134] = 0.f; row[135] = 0.f; }
  __syncthreads();

  float xv[14];
#pragma unroll
  for (int j = 0; j < 14; ++j) xv[j] = row[1 + w0 + j];

  const float* W3 = w3 + node * 6;  const float* B3 = b3 + node * 2;
  const float* W5 = w5 + node * 10; const float* B5 = b5 + node * 2;
  const float* W7 = w7 + node * 14; const float* B7 = b7 + node * 2;
  ushort* out = c + (size_t)br * CB + (size_t)(node * NB + b) * FFK + w0;

#pragma unroll
  for (int ch = 0; ch < 2; ++ch) {
    float k3[3], k5[5], k7[7];
#pragma unroll
    for (int j = 0; j < 3; ++j) k3[j] = W3[ch * 3 + j];
#pragma unroll
    for (int j = 0; j < 5; ++j) k5[j] = W5[ch * 5 + j];
#pragma unroll
    for (int j = 0; j < 7; ++j) k7[j] = W7[ch * 7 + j];
    float bb3 = B3[ch], bb5 = B5[ch], bb7 = B7[ch];
    ushort8v o3, o5, o7;
#pragma unroll
    for (int p = 0; p < 8; ++p) {
      float a3 = bb3, a5 = bb5, a7 = bb7;
#pragma unroll
      for (int j = 0; j < 3; ++j) a3 += k3[j] * xv[p + 2 + j];
#pragma unroll
      for (int j = 0; j < 5; ++j) a5 += k5[j] * xv[p + 1 + j];
#pragma unroll
      for (int j = 0; j < 7; ++j) a7 += k7[j] * xv[p + j];
      o3[p] = f2bf(fmaxf(a3, 0.f));
      o5[p] = f2bf(fmaxf(a5, 0.f));
      o7[p] = f2bf(fmaxf(a7, 0.f));
    }
    *reinterpret_cast<ushort8v*>(out + (0 + ch) * WIN) = o3;
    *reinterpret_cast<ushort8v*>(out + (2 + ch) * WIN) = o5;
    *reinterpret_cast<ushort8v*>(out + (4 + ch) * WIN) = o7;
  }
}

// ---------- BT GEMM body (XOR-swizzled LDS) ----------
template <int MODE>
DI void gemm_body(int bx, int by, const ushort* __restrict__ A, const ushort* __restrict__ A2,
                  const ushort* __restrict__ Bm, ushort* __restrict__ obf,
                  float* __restrict__ of, const float* __restrict__ bias) {
  constexpr int BN = (MODE == 2) ? 64 : 128;
  constexpr int KT = (MODE == 0) ? 12 : (MODE == 1) ? 4 : (MODE == 2) ? 8 : 4;
  constexpr int LDA = (MODE == 0) ? 768 : (MODE == 1) ? 256 : (MODE == 2) ? 256 : 6400;
  constexpr int LDB = (MODE == 0) ? 768 : (MODE == 1) ? 256 : (MODE == 2) ? 512 : 6400;
  constexpr int MF = (MODE == 2) ? 2 : 4;
  constexpr int NF = 4;

  __shared__ ushort As[128 * 64];
  __shared__ ushort Bs[BN * 64];

  const int tid = threadIdx.x, wv = tid >> 6, lane = tid & 63;
  const int j8 = (((lane & 7) ^ (lane >> 3)) - (lane & 7)) * 8;

  int mt = 0, nt = 0, node = 0, kbase = 0, br = 0;
  if constexpr (MODE == 0) {
    int h = bx;
    int s = (h & 7) * 100 + (h >> 3);
    nt = s & 1; int rest = s >> 1;
    mt = rest & 1; int yy = rest >> 1;
    br = yy >= 100; node = yy - br * 100;
  } else if constexpr (MODE == 1) {
    int h = bx;
    int s = (h & 7) * 100 + (h >> 3);
    nt = s & 1; int rest = s >> 1;
    br = rest >= 200; mt = rest - br * 200;
  } else if constexpr (MODE == 2) { mt = bx; node = by; }
  else { mt = bx; kbase = by * 256; }

  const ushort* Ab = nullptr; const ushort* Bb = nullptr;
  if constexpr (MODE == 0) { Ab = A + (size_t)br * CB + (size_t)node * (NB * FFK) + (size_t)mt * 128 * FFK;
                             Bb = Bm + (size_t)node * (GH * FFK) + (size_t)nt * 128 * FFK; }
  else if constexpr (MODE == 1) { Ab = A + (size_t)br * HB + (size_t)mt * 128 * GH;
                                  Bb = Bm + (size_t)nt * 128 * GH; }
  else if constexpr (MODE == 2) { Bb = Bm + (size_t)node * (DH * 512); }
  else { Ab = A + (size_t)mt * 128 * 6400 + kbase; Bb = Bm + kbase; }

  const int wr = (MODE == 2) ? wv : (wv >> 1);
  const int wc = (MODE == 2) ? 0 : (wv & 1);

  f32x4 acc[MF][NF] = {};

  for (int kt = 0; kt < KT; ++kt) {
    const int k0 = kt * 64;
    __syncthreads();
#pragma unroll
    for (int it = 0; it < 4; ++it) {
      int rb = it * 32 + wv * 8;
      int row = rb + (lane >> 3);
      const ushort* gp;
      if constexpr (MODE == 2) {
        int b_ = mt * 128 + row;
        const ushort* src = (k0 < 256) ? A : A2;
        gp = src + (size_t)(b_ * NNODE + node) * GH + (k0 & 255) + (lane & 7) * 8 + j8;
      } else {
        gp = Ab + (size_t)row * LDA + k0 + (lane & 7) * 8 + j8;
      }
      gload16(gp, &As[rb * 64]);
    }
#pragma unroll
    for (int it = 0; it < BN / 32; ++it) {
      int rb = it * 32 + wv * 8;
      int row = rb + (lane >> 3);
      gload16(Bb + (size_t)row * LDB + k0 + (lane & 7) * 8 + j8, &Bs[rb * 64]);
    }
    __syncthreads();
#pragma unroll
    for (int kk = 0; kk < 2; ++kk) {
      const int ch8 = ((kk * 4 + (lane >> 4)) ^ (lane & 7)) * 8;
      bf16x8 af[MF], bfr[NF];
#pragma unroll
      for (int m = 0; m < MF; ++m) {
        int rr = wr * (MF * 16) + m * 16 + (lane & 15);
        af[m] = *reinterpret_cast<const bf16x8*>(&As[rr * 64 + ch8]);
      }
#pragma unroll
      for (int n = 0; n < NF; ++n) {
        int rr = wc * 64 + n * 16 + (lane & 15);
        bfr[n] = *reinterpret_cast<const bf16x8*>(&Bs[rr * 64 + ch8]);
      }
#pragma unroll
      for (int m = 0; m < MF; ++m)
#pragma unroll
        for (int n = 0; n < NF; ++n)
          acc[m][n] = __builtin_amdgcn_mfma_f32_16x16x32_bf16(af[m], bfr[n], acc[m][n], 0, 0, 0);
    }
  }

  const int lrow = (lane >> 4) * 4, lcol = lane & 15;
#pragma unroll
  for (int m = 0; m < MF; ++m) {
#pragma unroll
    for (int n = 0; n < NF; ++n) {
      int cc = wc * 64 + n * 16 + lcol;
#pragma unroll
      for (int rg = 0; rg < 4; ++rg) {
        int rr = wr * (MF * 16) + m * 16 + lrow + rg;
        float val = acc[m][n][rg];
        if constexpr (MODE == 0) {
          int b_ = mt * 128 + rr;
          int col = nt * 128 + cc;
          val = fmaxf(val + bias[node * GH + col], 0.f);
          obf[(size_t)br * HB + (size_t)(b_ * NNODE + node) * GH + col] = f2bf(val);
        } else if constexpr (MODE == 1) {
          int R = mt * 128 + rr;
          int col = nt * 128 + cc;
          obf[(size_t)br * HB + (size_t)R * GH + col] = f2bf(val * bias[br * NTOT + R]);
        } else if constexpr (MODE == 2) {
          int b_ = mt * 128 + rr;
          val = fmaxf(val + bias[node * DH + cc], 0.f);
          obf[(size_t)b_ * (NNODE * DH) + node * DH + cc] = f2bf(val);
        } else {
          int R = mt * 128 + rr;
          if (by == 0) val += bias[cc];
          atomicAdd(&of[R * OUTC + cc], val);
        }
      }
    }
  }
}

// ================= fused launch kernels =================

// F1: [histseg 128][conv 3200][cvt 23264] — all atomic-free BW work; shared buffer unioned
__global__ __launch_bounds__(256) void fused1_k(
    const float* __restrict__ Wff, const float* __restrict__ Wd,
    const float* __restrict__ Wfc, const float* __restrict__ Wg,
    ushort* __restrict__ Wffb, ushort* __restrict__ Wdb,
    ushort* __restrict__ Wfcb, ushort* __restrict__ Wgb,
    const int* __restrict__ e1d, const int* __restrict__ e2d,
    ushort* __restrict__ rank_local, uint* __restrict__ segcnt,
    const float* __restrict__ x1, const float* __restrict__ x2,
    const float* __restrict__ w3, const float* __restrict__ b3,
    const float* __restrict__ w5, const float* __restrict__ b5,
    const float* __restrict__ w7, const float* __restrict__ b7,
    ushort* __restrict__ c) {
  __shared__ uint smem[NPK];   // 50 KB; conv reuses as float[16][136]
  int bx = blockIdx.x;
  if (bx < 128) histseg_body(bx, e1d, e2d, rank_local, segcnt, smem);
  else if (bx < 3328) conv_body(bx - 128, x1, x2, w3, b3, w5, b5, w7, b7, c, (float*)smem);
  else cvt_body(bx - 3328, Wff, Wd, Wfc, Wg, Wffb, Wdb, Wfcb, Wgb);
}

// per-dst running sum over segments: segbase (packed) + deg
__global__ __launch_bounds__(256) void segscan_k(const uint* __restrict__ segcnt,
                                                 uint* __restrict__ segbase, int* __restrict__ deg) {
  int set = blockIdx.y;
  int p = blockIdx.x * 256 + threadIdx.x;   // [0, NPK)
  uint lo = 0, hi = 0;
  const uint* sc = segcnt + (size_t)set * NSEG * NPK + p;
  uint* sb = segbase + (size_t)set * NSEG * NPK + p;
  for (int s = 0; s < NSEG; ++s) {
    uint v = sc[(size_t)s * NPK];
    sb[(size_t)s * NPK] = lo | (hi << 16);
    lo += v & 0xffffu; hi += v >> 16;
  }
  reinterpret_cast<int2*>(deg)[set * NPK + p] = make_int2((int)lo, (int)hi);
}

__global__ __launch_bounds__(256) void scan_k(const int* __restrict__ deg,
                                              int* __restrict__ offs, float* __restrict__ nrm) {
  scan_body(blockIdx.x, deg, offs, nrm);
}

// F3: FF GEMM || atomic-free CSR fill
__global__ __launch_bounds__(256) void fused3_k(
    const ushort* __restrict__ cbuf, const ushort* __restrict__ Wffb,
    ushort* __restrict__ h, const float* __restrict__ bff,
    const int* __restrict__ e1, const int* __restrict__ e2,
    const int* __restrict__ offs, const ushort* __restrict__ rank_local,
    const uint* __restrict__ segbase, int* __restrict__ csr) {
  if ((int)blockIdx.x < 800)
    gemm_body<0>(blockIdx.x, 0, cbuf, nullptr, Wffb, h, nullptr, bff);
  else
    fill_body(blockIdx.x - 800, e1, e2, offs, rank_local, segbase, csr);
}

template <int MODE>
__global__ __launch_bounds__(256) void gemm_k(const ushort* __restrict__ A, const ushort* __restrict__ A2,
                                              const ushort* __restrict__ Bm, ushort* __restrict__ obf,
                                              float* __restrict__ of, const float* __restrict__ bias) {
  gemm_body<MODE>(blockIdx.x, blockIdx.y, A, A2, Bm, obf, of, bias);
}

// ---------- GCN aggregation, both branches: one wave per dst node ----------
__global__ __launch_bounds__(256) void agg_k(const ushort* __restrict__ xw_, const int* __restrict__ offs_,
                                             const int* __restrict__ csr_, const float* __restrict__ norm_,
                                             const float* __restrict__ bg, ushort* __restrict__ hg_) {
  int idx = blockIdx.x * 4 + (threadIdx.x >> 6);   // [0, 51200)
  int br = idx >= NTOT;
  int v = idx - br * NTOT;
  const ushort* xw = xw_ + (size_t)br * HB;
  const int* offs = offs_ + br * (NTOT + 1);
  const int* csr = csr_ + br * NE;
  const float* norm = norm_ + br * NTOT;
  ushort* hg = hg_ + (size_t)br * HB;

  int lane = threadIdx.x & 63;
  int half = lane >> 5;
  int colb = (lane & 31) * 8;
  const ushort* base = xw + colb;

  float a[8] = {0.f, 0.f, 0.f, 0.f, 0.f, 0.f, 0.f, 0.f};
  if (half == 0) {
    ushort8v q = *reinterpret_cast<const ushort8v*>(base + (size_t)v * GH);
#pragma unroll
    for (int i = 0; i < 8; ++i) a[i] += bf2f(q[i]);
  }
  int e0 = offs[v], e1 = offs[v + 1];
  int j = e0 + half;
  for (; j + 6 < e1; j += 8) {
    int s0 = csr[j], s1 = csr[j + 2], s2 = csr[j + 4], s3 = csr[j + 6];
    ushort8v q0 = *reinterpret_cast<const ushort8v*>(base + (size_t)s0 * GH);
    ushort8v q1 = *reinterpret_cast<const ushort8v*>(base + (size_t)s1 * GH);
    ushort8v q2 = *reinterpret_cast<const ushort8v*>(base + (size_t)s2 * GH);
    ushort8v q3 = *reinterpret_cast<const ushort8v*>(base + (size_t)s3 * GH);
#pragma unroll
    for (int i = 0; i < 8; ++i)
      a[i] += (bf2f(q0[i]) + bf2f(q1[i])) + (bf2f(q2[i]) + bf2f(q3[i]));
  }
  for (; j + 2 < e1; j += 4) {
    int s0 = csr[j], s1 = csr[j + 2];
    ushort8v q0 = *reinterpret_cast<const ushort8v*>(base + (size_t)s0 * GH);
    ushort8v q1 = *reinterpret_cast<const ushort8v*>(base + (size_t)s1 * GH);
#pragma unroll
    for (int i = 0; i < 8; ++i) a[i] += bf2f(q0[i]) + bf2f(q1[i]);
  }
  if (j < e1) {
    int s0 = csr[j];
    ushort8v q0 = *reinterpret_cast<const ushort8v*>(base + (size_t)s0 * GH);
#pragma unroll
    for (int i = 0; i < 8; ++i) a[i] += bf2f(q0[i]);
  }
#pragma unroll
  for (int i = 0; i < 8; ++i) a[i] += __shfl_xor(a[i], 32);

  if (half == 0) {
    float nv = norm[v];
    float4 bb0 = *reinterpret_cast<const float4*>(bg + colb);
    float4 bb1 = *reinterpret_cast<const float4*>(bg + colb + 4);
    ushort8v o;
    o[0] = f2bf(fmaxf(nv * a[0] + bb0.x, 0.f));
    o[1] = f2bf(fmaxf(nv * a[1] + bb0.y, 0.f));
    o[2] = f2bf(fmaxf(nv * a[2] + bb0.z, 0.f));
    o[3] = f2bf(fmaxf(nv * a[3] + bb0.w, 0.f));
    o[4] = f2bf(fmaxf(nv * a[4] + bb1.x, 0.f));
    o[5] = f2bf(fmaxf(nv * a[5] + bb1.y, 0.f));
    o[6] = f2bf(fmaxf(nv * a[6] + bb1.z, 0.f));
    o[7] = f2bf(fmaxf(nv * a[7] + bb1.w, 0.f));
    *reinterpret_cast<ushort8v*>(hg + (size_t)v * GH + colb) = o;
  }
}

extern "C" void kernel_launch(void* const* d_in, const int* in_sizes, int n_in,
                              void* d_out, int out_size, void* d_ws, size_t ws_size,
                              hipStream_t stream) {
  const float* x1 = (const float*)d_in[0];
  const float* x2 = (const float*)d_in[1];
  const int* e1 = (const int*)d_in[2];
  const int* e2 = (const int*)d_in[3];
  const float* w3 = (const float*)d_in[4];  const float* b3 = (const float*)d_in[5];
  const float* w5 = (const float*)d_in[6];  const float* b5 = (const float*)d_in[7];
  const float* w7 = (const float*)d_in[8];  const float* b7 = (const float*)d_in[9];
  const float* Wff = (const float*)d_in[10]; const float* bff = (const float*)d_in[11];
  const float* Wg = (const float*)d_in[12];  const float* bg = (const float*)d_in[13];
  const float* Wd = (const float*)d_in[14];  const float* bd = (const float*)d_in[15];
  const float* Wfc = (const float*)d_in[16]; const float* bfc = (const float*)d_in[17];
  float* out = (float*)d_out;

  char* ws = (char*)d_ws;
  size_t off = 0;
  auto alloc = [&](size_t bytes) -> char* {
    char* p = ws + off;
    off = (off + bytes + 255) & ~(size_t)255;
    return p;
  };
  ushort* Wffb = (ushort*)alloc(19660800ull * 2);
  ushort* Wdb  = (ushort*)alloc(3276800ull * 2);
  ushort* Wfcb = (ushort*)alloc(819200ull * 2);
  ushort* Wgb  = (ushort*)alloc(65536ull * 2);
  ushort* cbuf = (ushort*)alloc(2 * CB * 2);   // both branches; later aliased as du
  ushort* h    = (ushort*)alloc(2 * HB * 2);   // both branches; later aliased as hg
  ushort* xw   = (ushort*)alloc(2 * HB * 2);   // both branches
  int* deg     = (int*)alloc(2 * NTOT * 4);
  int* offs    = (int*)alloc(2 * (NTOT + 1) * 4);
  ushort* rankl = (ushort*)alloc(2 * NE * 2);
  uint* segcnt  = (uint*)alloc((size_t)2 * NSEG * NPK * 4);
  uint* segbase = (uint*)alloc((size_t)2 * NSEG * NPK * 4);
  int* csr     = (int*)alloc(2 * NE * 4);
  float* nrm   = (float*)alloc(2 * NTOT * 4);
  ushort* du = cbuf;  // alias: cbuf free after FF GEMM

  hipMemsetAsync(out, 0, (size_t)out_size * 4, stream);

  // F1: histseg (LDS histogram, no global atomics) + conv + cvt, all BW-bound
  fused1_k<<<128 + 3200 + CVT_BLKS, 256, 0, stream>>>(
      Wff, Wd, Wfc, Wg, Wffb, Wdb, Wfcb, Wgb,
      e1 + NE, e2 + NE, rankl, segcnt,
      x1, x2, w3, b3, w5, b5, w7, b7, cbuf);
  // per-dst segment scan -> segbase + deg
  segscan_k<<<dim3(NPK / 256, 2), 256, 0, stream>>>(segcnt, segbase, deg);
  // offsets + norms
  scan_k<<<2, 256, 0, stream>>>(deg, offs, nrm);
  // F3: FF GEMM || atomic-free CSR fill
  fused3_k<<<4000, 256, 0, stream>>>(cbuf, Wffb, h, bff, e1, e2, offs, rankl, segbase, csr);

  gemm_k<1><<<800, 256, 0, stream>>>(h, nullptr, Wgb, xw, nullptr, nrm);
  agg_k<<<12800, 256, 0, stream>>>(xw, offs, csr, nrm, bg, h);   // hg overwrites h

  gemm_k<2><<<dim3(2, 100), 256, 0, stream>>>(h, h + HB, Wdb, du, nullptr, bd);
  gemm_k<3><<<dim3(2, 25), 256, 0, stream>>>(du, nullptr, Wfcb, nullptr, out, bfc);
}